// Round 12
// baseline (201.794 us; speedup 1.0000x reference)
//
#include <hip/hip_runtime.h>
#include <hip/hip_fp16.h>
#include <math.h>

#define NN 50000
#define DD 128
#define CC 64
#define EE 800000
#define IND 384

typedef __attribute__((ext_vector_type(8))) _Float16 h8v;
typedef __attribute__((ext_vector_type(4))) float f4v;

static __device__ __forceinline__ unsigned short f2h(float f) {
  _Float16 h = (_Float16)f;
  return *reinterpret_cast<unsigned short*>(&h);
}
static __device__ __forceinline__ float h2f(unsigned short u) {
  _Float16 h = *reinterpret_cast<_Float16*>(&u);
  return (float)h;
}
static __device__ __forceinline__ float hlo(unsigned int u) {
  return h2f((unsigned short)(u & 0xffffu));
}
static __device__ __forceinline__ float hhi(unsigned int u) {
  return h2f((unsigned short)(u >> 16));
}
static __device__ __forceinline__ h8v hzero() {
  h8v v = {0, 0, 0, 0, 0, 0, 0, 0};
  return v;
}

// ---- zero the degree-count array ----
__global__ __launch_bounds__(256) void k_zero(int4* __restrict__ cnt4, int n4) {
  int i = blockIdx.x * 256 + threadIdx.x;
  if (i < n4) cnt4[i] = make_int4(0, 0, 0, 0);
}

// ---- edge in-degree count + per-edge rank ----
__global__ __launch_bounds__(256) void k_count(const int* __restrict__ dst,
                                               int* __restrict__ cnt,
                                               int* __restrict__ rank) {
  int e = blockIdx.x * 256 + threadIdx.x;
  if (e < EE) rank[e] = atomicAdd(&cnt[dst[e]], 1);
}

// ---------------- hierarchical exclusive scan ----------------
__global__ __launch_bounds__(1024) void k_scan1(const int* __restrict__ cnt,
                                                int* __restrict__ rowstart,
                                                float* __restrict__ dinv,
                                                int* __restrict__ bsum) {
  __shared__ int wsum[16];
  int tid = threadIdx.x;
  int wave = tid >> 6, lane = tid & 63;
  int i = blockIdx.x * 1024 + tid;
  int v = (i < NN) ? cnt[i] : 0;
  int x = v;
#pragma unroll
  for (int off = 1; off < 64; off <<= 1) {
    int t = __shfl_up(x, off);
    if (lane >= off) x += t;
  }
  if (lane == 63) wsum[wave] = x;
  __syncthreads();
  if (wave == 0 && lane < 16) {
    int y = wsum[lane];
#pragma unroll
    for (int off = 1; off < 16; off <<= 1) {
      int t = __shfl_up(y, off);
      if (lane >= off) y += t;
    }
    wsum[lane] = y;
  }
  __syncthreads();
  int ex = (wave ? wsum[wave - 1] : 0) + x - v;
  if (i < NN) {
    rowstart[i] = ex;
    dinv[i] = 1.0f / sqrtf((float)(v + 1));
  }
  if (tid == 1023) bsum[blockIdx.x] = wsum[15];
}

__global__ __launch_bounds__(64) void k_scan2(int* __restrict__ bsum,
                                              int* __restrict__ rowstart,
                                              int nb) {
  int lane = threadIdx.x;
  int v = (lane < nb) ? bsum[lane] : 0;
  int x = v;
#pragma unroll
  for (int off = 1; off < 64; off <<= 1) {
    int t = __shfl_up(x, off);
    if (lane >= off) x += t;
  }
  if (lane < nb) bsum[lane] = x - v;
  if (lane == 0) rowstart[NN] = EE;
}

__global__ __launch_bounds__(1024) void k_scan3(int* __restrict__ rowstart,
                                                const int* __restrict__ bsum) {
  int i = blockIdx.x * 1024 + threadIdx.x;
  if (i < NN) rowstart[i] += bsum[blockIdx.x];
}

// ---- CSR placement, atomic-free, ushort col ----
__global__ __launch_bounds__(256) void k_place(const int* __restrict__ src,
                                               const int* __restrict__ dst,
                                               const int* __restrict__ rank,
                                               const int* __restrict__ rowstart,
                                               unsigned short* __restrict__ col) {
  int e = blockIdx.x * 256 + threadIdx.x;
  if (e < EE) {
    int d = dst[e];
    col[rowstart[d] + rank[e]] = (unsigned short)src[e];
  }
}

// ---- per-node logmap scales with dinv folded ----
__global__ __launch_bounds__(256) void k_scal(const float* __restrict__ xH,
                                              const float* __restrict__ xS,
                                              const float* __restrict__ dinv,
                                              float* __restrict__ sc1,
                                              float* __restrict__ sc2) {
  int gw = (blockIdx.x * 256 + threadIdx.x) >> 6;
  int lane = threadIdx.x & 63;
  if (gw >= NN) return;
  const float2* h2 = (const float2*)(xH) + (size_t)gw * 64;
  float2 vh = h2[lane];
  float ssh = vh.x * vh.x + vh.y * vh.y;
  if (lane == 0) ssh -= vh.x * vh.x;  // direct sum over x[1:]
#pragma unroll
  for (int off = 32; off; off >>= 1) ssh += __shfl_down(ssh, off);
  const float2* s2 = (const float2*)(xS) + (size_t)gw * 64;
  float2 vs = s2[lane];
  float sss = vs.x * vs.x + vs.y * vs.y;
  if (lane == 0) sss -= vs.x * vs.x;
#pragma unroll
  for (int off = 32; off; off >>= 1) sss += __shfl_down(sss, off);
  if (lane == 0) {
    float dv = dinv[gw];
    float nrh = sqrtf(ssh);
    float dist = acoshf(fmaxf(vh.x, 1.0f));
    sc1[gw] = dv * dist / fmaxf(nrh, 1e-12f);
    float nrs = sqrtf(sss);
    float th = acosf(fminf(fmaxf(vs.x, -1.0f), 1.0f));
    sc2[gw] = dv * th / fmaxf(nrs, 1e-12f);
  }
}

// ---------------- W transpose + fp16: Wt[128][384] ----------------
__global__ __launch_bounds__(256) void k_wprep(const float* __restrict__ W,
                                               unsigned short* __restrict__ Wt) {
  int flat = blockIdx.x * 256 + threadIdx.x;
  if (flat >= IND * DD) return;
  int n = flat / IND;
  int k = flat - n * IND;
  Wt[(size_t)n * IND + k] = f2h(W[(size_t)k * DD + n]);
}

// ---- MFMA fp16 GEMM; output in quarter-plane layout hq[4][NN][32] ----
__global__ __launch_bounds__(256) void k_gemm(const float* __restrict__ xE,
                                              const float* __restrict__ xH,
                                              const float* __restrict__ xS,
                                              const float* __restrict__ dinv,
                                              const float* __restrict__ sc1,
                                              const float* __restrict__ sc2,
                                              const unsigned short* __restrict__ Wt,
                                              unsigned short* __restrict__ hq) {
  __shared__ unsigned short Ah[64 * 64];  // 8 KB
  int tid = threadIdx.x;
  int lane = tid & 63;
  int wid = tid >> 6;
  int wr = wid >> 1, wc = wid & 1;
  int r0 = wr * 32, c0 = wc * 64;
  int bm0 = blockIdx.x * 64;
  int l15 = lane & 15;
  int lhi = lane >> 4;

  f4v acc[2][4];
#pragma unroll
  for (int m = 0; m < 2; ++m)
#pragma unroll
    for (int nf = 0; nf < 4; ++nf) acc[m][nf] = f4v{0.f, 0.f, 0.f, 0.f};

  for (int kb = 0; kb < IND; kb += 64) {
    int sec = kb >> 7;
    int off = kb & 127;
    const float* __restrict__ src = (sec == 0) ? xE : (sec == 1) ? xH : xS;
#pragma unroll
    for (int it = 0; it < 4; ++it) {
      int flat = tid + it * 256;
      int row = flat >> 4;
      int f4 = flat & 15;
      int node = bm0 + row;
      float4 v = make_float4(0.f, 0.f, 0.f, 0.f);
      float scale = 0.f;
      if (node < NN) {
        v = *(const float4*)&src[(size_t)node * DD + off + f4 * 4];
        scale = (sec == 0) ? dinv[node] : (sec == 1) ? sc1[node] : sc2[node];
      }
      v.x *= scale; v.y *= scale; v.z *= scale; v.w *= scale;
      if (sec > 0 && off == 0 && f4 == 0) v.x = 0.f;  // logmap zero column
      ushort4 o;
      o.x = f2h(v.x); o.y = f2h(v.y); o.z = f2h(v.z); o.w = f2h(v.w);
      int idx = (row * 64 + f4 * 4) ^ ((row & 7) << 3);
      *(ushort4*)&Ah[idx] = o;
    }
    __syncthreads();
#pragma unroll
    for (int ks = 0; ks < 2; ++ks) {
      h8v a[2];
#pragma unroll
      for (int m = 0; m < 2; ++m) {
        int row = r0 + m * 16 + l15;
        int idx = (row * 64 + ks * 32 + lhi * 8) ^ ((row & 7) << 3);
        a[m] = *reinterpret_cast<const h8v*>(&Ah[idx]);
      }
      int kk = kb + ks * 32 + lhi * 8;
#pragma unroll
      for (int nf = 0; nf < 4; ++nf) {
        int n = c0 + nf * 16 + l15;
        h8v b = *reinterpret_cast<const h8v*>(&Wt[(size_t)n * IND + kk]);
#pragma unroll
        for (int m = 0; m < 2; ++m)
          acc[m][nf] = __builtin_amdgcn_mfma_f32_16x16x32_f16(a[m], b, acc[m][nf], 0, 0, 0);
      }
    }
    __syncthreads();
  }
#pragma unroll
  for (int m = 0; m < 2; ++m)
#pragma unroll
    for (int nf = 0; nf < 4; ++nf) {
      int colx = c0 + nf * 16 + l15;
      int q = colx >> 5;
      int w32 = colx & 31;
      int rowb = bm0 + r0 + m * 16 + lhi * 4;
#pragma unroll
      for (int j = 0; j < 4; ++j) {
        int node = rowb + j;
        if (node < NN)
          hq[(size_t)q * NN * 32 + (size_t)node * 32 + w32] = f2h(acc[m][nf][j]);
      }
    }
}

// ---------------- normalize class embeddings -> packed fp16 [64][128] --------
__global__ __launch_bounds__(256) void k_cprep(const float* __restrict__ cls,
                                               unsigned int* __restrict__ clsp) {
  int wave = threadIdx.x >> 6, lane = threadIdx.x & 63;
  for (int c = wave; c < CC; c += 4) {
    const float2* r2 = (const float2*)(cls + (size_t)c * DD);
    float2 v = r2[lane];
    float ss = v.x * v.x + v.y * v.y;
#pragma unroll
    for (int off = 32; off; off >>= 1) ss += __shfl_xor(ss, off);
    float inv = 1.0f / fmaxf(sqrtf(ss), 1e-8f);
    clsp[c * 64 + lane] =
        (unsigned int)f2h(v.x * inv) | ((unsigned int)f2h(v.y * inv) << 16);
  }
}

// ---- dimension-sharded aggregation: one 3.2MB quarter-plane per launch ----
// block 256 = 4 waves x 4 subgroups(16 lanes) = 16 nodes; 3125 blocks exact.
__global__ __launch_bounds__(256) void k_aggq(const unsigned int* __restrict__ hqp,
                                              const int* __restrict__ rowstart,
                                              const unsigned short* __restrict__ col,
                                              const float* __restrict__ dinv,
                                              const float* __restrict__ b,
                                              int q,
                                              unsigned int* __restrict__ xgqp,
                                              float* __restrict__ psp) {
  int tid = threadIdx.x;
  int wid = tid >> 6;
  int subg = (tid >> 4) & 3;
  int li = tid & 15;
  int nb = blockIdx.x * 16 + wid * 4 + subg;  // 0..49999 exact

  unsigned int hv = hqp[(size_t)nb * 16 + li];  // self (h pre-scaled by dinv[src])
  float ax = hlo(hv), ay = hhi(hv);
  int s = rowstart[nb], e = rowstart[nb + 1];
  int j = s;
  for (; j + 7 < e; j += 8) {
    int cc[8];
    unsigned int vv[8];
#pragma unroll
    for (int t = 0; t < 8; ++t) cc[t] = col[j + t];
#pragma unroll
    for (int t = 0; t < 8; ++t) vv[t] = hqp[(size_t)cc[t] * 16 + li];
#pragma unroll
    for (int t = 0; t < 8; ++t) {
      ax += hlo(vv[t]);
      ay += hhi(vv[t]);
    }
  }
  for (; j < e; ++j) {
    unsigned int v = hqp[(size_t)col[j] * 16 + li];
    ax += hlo(v);
    ay += hhi(v);
  }
  float dv = dinv[nb];
  float2 bb = ((const float2*)b)[q * 16 + li];
  float rx = dv * ax + bb.x;
  float ry = dv * ay + bb.y;
  float ss = rx * rx + ry * ry;
#pragma unroll
  for (int off = 8; off; off >>= 1) ss += __shfl_xor(ss, off);  // 16-lane reduce
  xgqp[(size_t)nb * 16 + li] =
      (unsigned int)f2h(rx) | ((unsigned int)f2h(ry) << 16);
  if (li == 0) psp[nb] = ss;
}

// ---- reassemble quarters, normalize -> xn fp16 [NN][128] ----
__global__ __launch_bounds__(256) void k_norm(const unsigned int* __restrict__ xgq,
                                              const float* __restrict__ ps,
                                              unsigned int* __restrict__ xn) {
  int node = (blockIdx.x * 256 + threadIdx.x) >> 6;
  int u = threadIdx.x & 63;
  if (node >= NN) return;
  float ssq = ps[node] + ps[NN + node] + ps[2 * NN + node] + ps[3 * NN + node];
  float inv = 1.0f / fmaxf(sqrtf(ssq), 1e-8f);
  unsigned int v = xgq[(size_t)(u >> 4) * NN * 16 + (size_t)node * 16 + (u & 15)];
  xn[(size_t)node * 64 + u] =
      (unsigned int)f2h(hlo(v) * inv) | ((unsigned int)f2h(hhi(v) * inv) << 16);
}

// ---- classifier fp16 MFMA GEMM: out = xn @ clsn^T ----
__global__ __launch_bounds__(256) void k_outg(const unsigned short* __restrict__ xn,
                                              const unsigned short* __restrict__ clsp,
                                              float* __restrict__ out) {
  int tid = threadIdx.x;
  int lane = tid & 63;
  int wid = tid >> 6;
  int l15 = lane & 15, lhi = lane >> 4;
  int bm0 = blockIdx.x * 128 + wid * 32;

  f4v acc[2][4];
#pragma unroll
  for (int m = 0; m < 2; ++m)
#pragma unroll
    for (int nf = 0; nf < 4; ++nf) acc[m][nf] = f4v{0.f, 0.f, 0.f, 0.f};

#pragma unroll
  for (int ks = 0; ks < 4; ++ks) {
    h8v a[2];
#pragma unroll
    for (int m = 0; m < 2; ++m) {
      int row = bm0 + m * 16 + l15;
      a[m] = (row < NN)
                 ? *reinterpret_cast<const h8v*>(&xn[(size_t)row * DD + ks * 32 + lhi * 8])
                 : hzero();
    }
#pragma unroll
    for (int nf = 0; nf < 4; ++nf) {
      int n = nf * 16 + l15;
      h8v b = *reinterpret_cast<const h8v*>(&clsp[(size_t)n * DD + ks * 32 + lhi * 8]);
#pragma unroll
      for (int m = 0; m < 2; ++m)
        acc[m][nf] = __builtin_amdgcn_mfma_f32_16x16x32_f16(a[m], b, acc[m][nf], 0, 0, 0);
    }
  }
#pragma unroll
  for (int m = 0; m < 2; ++m)
#pragma unroll
    for (int nf = 0; nf < 4; ++nf) {
      int colx = nf * 16 + l15;
      int rowb = bm0 + m * 16 + lhi * 4;
#pragma unroll
      for (int j = 0; j < 4; ++j) {
        int row = rowb + j;
        if (row < NN) out[(size_t)row * CC + colx] = acc[m][nf][j];
      }
    }
}

extern "C" void kernel_launch(void* const* d_in, const int* in_sizes, int n_in,
                              void* d_out, int out_size, void* d_ws, size_t ws_size,
                              hipStream_t stream) {
  const float* xE = (const float*)d_in[0];
  const float* xH = (const float*)d_in[1];
  const float* xS = (const float*)d_in[2];
  const int* ei = (const int*)d_in[3];
  const float* W = (const float*)d_in[4];
  const float* b = (const float*)d_in[5];
  const float* cls = (const float*)d_in[6];
  float* out = (float*)d_out;

  char* ws = (char*)d_ws;
  size_t off = 0;
  auto alloc = [&](size_t bytes) {
    void* p = ws + off;
    off = (off + bytes + 255) & ~(size_t)255;
    return p;
  };
  unsigned short* hq = (unsigned short*)alloc((size_t)NN * DD * 2);     // 4 planes
  unsigned int* xgq = (unsigned int*)alloc((size_t)NN * 64 * 4);        // 4 planes
  unsigned int* xn = (unsigned int*)alloc((size_t)NN * 64 * 4);
  float* ps = (float*)alloc((size_t)4 * NN * 4);
  float* dinv = (float*)alloc((size_t)NN * 4);
  float* sc1 = (float*)alloc((size_t)NN * 4);
  float* sc2 = (float*)alloc((size_t)NN * 4);
  int* cnt = (int*)alloc((size_t)(NN + 16) * 4);
  int* rowst = (int*)alloc((size_t)(NN + 1) * 4);
  int* rank = (int*)alloc((size_t)EE * 4);
  unsigned short* col = (unsigned short*)alloc((size_t)EE * 2);
  unsigned short* Wt = (unsigned short*)alloc((size_t)DD * IND * 2);
  unsigned int* clsp = (unsigned int*)alloc((size_t)CC * 64 * 4);
  int* bsum = (int*)alloc(64 * 4);

  const int* esrc = ei;
  const int* edst = ei + EE;
  const int NB = (NN + 1023) / 1024;
  const int N4 = (NN + 3) / 4;

  k_zero<<<(N4 + 255) / 256, 256, 0, stream>>>((int4*)cnt, N4);
  k_count<<<(EE + 255) / 256, 256, 0, stream>>>(edst, cnt, rank);
  k_scan1<<<NB, 1024, 0, stream>>>(cnt, rowst, dinv, bsum);
  k_scan2<<<1, 64, 0, stream>>>(bsum, rowst, NB);
  k_scan3<<<NB, 1024, 0, stream>>>(rowst, bsum);
  k_place<<<(EE + 255) / 256, 256, 0, stream>>>(esrc, edst, rank, rowst, col);
  k_wprep<<<(IND * DD + 255) / 256, 256, 0, stream>>>(W, Wt);
  k_cprep<<<1, 256, 0, stream>>>(cls, clsp);
  k_scal<<<(NN + 3) / 4, 256, 0, stream>>>(xH, xS, dinv, sc1, sc2);
  k_gemm<<<(NN + 63) / 64, 256, 0, stream>>>(xE, xH, xS, dinv, sc1, sc2, Wt, hq);
  for (int q = 0; q < 4; ++q) {
    k_aggq<<<NN / 16, 256, 0, stream>>>((const unsigned int*)hq + (size_t)q * NN * 16,
                                        rowst, col, dinv, b, q,
                                        xgq + (size_t)q * NN * 16, ps + (size_t)q * NN);
  }
  k_norm<<<(NN + 3) / 4, 256, 0, stream>>>(xgq, ps, xn);
  k_outg<<<(NN + 127) / 128, 256, 0, stream>>>((const unsigned short*)xn,
                                               (const unsigned short*)clsp, out);
}

// Round 13
// 168.337 us; speedup vs baseline: 1.1988x; 1.1988x over previous
//
#include <hip/hip_runtime.h>
#include <hip/hip_fp16.h>
#include <math.h>

#define NN 50000
#define DD 128
#define CC 64
#define EE 800000
#define IND 384

typedef __attribute__((ext_vector_type(8))) _Float16 h8v;
typedef __attribute__((ext_vector_type(4))) float f4v;

static __device__ __forceinline__ unsigned short f2h(float f) {
  _Float16 h = (_Float16)f;
  return *reinterpret_cast<unsigned short*>(&h);
}
static __device__ __forceinline__ float h2f(unsigned short u) {
  _Float16 h = *reinterpret_cast<_Float16*>(&u);
  return (float)h;
}
static __device__ __forceinline__ float hlo(unsigned int u) {
  return h2f((unsigned short)(u & 0xffffu));
}
static __device__ __forceinline__ float hhi(unsigned int u) {
  return h2f((unsigned short)(u >> 16));
}
static __device__ __forceinline__ h8v hzero() {
  h8v v = {0, 0, 0, 0, 0, 0, 0, 0};
  return v;
}

// ---- zero the degree-count array ----
__global__ __launch_bounds__(256) void k_zero(int4* __restrict__ cnt4, int n4) {
  int i = blockIdx.x * 256 + threadIdx.x;
  if (i < n4) cnt4[i] = make_int4(0, 0, 0, 0);
}

// ---- edge in-degree count + per-edge rank (ushort, coalesced) ----
__global__ __launch_bounds__(256) void k_count(const int* __restrict__ dst,
                                               int* __restrict__ cnt,
                                               unsigned short* __restrict__ rank) {
  int e = blockIdx.x * 256 + threadIdx.x;
  if (e < EE) rank[e] = (unsigned short)atomicAdd(&cnt[dst[e]], 1);
}

// ---------------- hierarchical exclusive scan ----------------
__global__ __launch_bounds__(1024) void k_scan1(const int* __restrict__ cnt,
                                                int* __restrict__ rowstart,
                                                float* __restrict__ dinv,
                                                int* __restrict__ bsum) {
  __shared__ int wsum[16];
  int tid = threadIdx.x;
  int wave = tid >> 6, lane = tid & 63;
  int i = blockIdx.x * 1024 + tid;
  int v = (i < NN) ? cnt[i] : 0;
  int x = v;
#pragma unroll
  for (int off = 1; off < 64; off <<= 1) {
    int t = __shfl_up(x, off);
    if (lane >= off) x += t;
  }
  if (lane == 63) wsum[wave] = x;
  __syncthreads();
  if (wave == 0 && lane < 16) {
    int y = wsum[lane];
#pragma unroll
    for (int off = 1; off < 16; off <<= 1) {
      int t = __shfl_up(y, off);
      if (lane >= off) y += t;
    }
    wsum[lane] = y;
  }
  __syncthreads();
  int ex = (wave ? wsum[wave - 1] : 0) + x - v;
  if (i < NN) {
    rowstart[i] = ex;
    dinv[i] = 1.0f / sqrtf((float)(v + 1));
  }
  if (tid == 1023) bsum[blockIdx.x] = wsum[15];
}

__global__ __launch_bounds__(64) void k_scan2(int* __restrict__ bsum,
                                              int* __restrict__ rowstart,
                                              int nb) {
  int lane = threadIdx.x;
  int v = (lane < nb) ? bsum[lane] : 0;
  int x = v;
#pragma unroll
  for (int off = 1; off < 64; off <<= 1) {
    int t = __shfl_up(x, off);
    if (lane >= off) x += t;
  }
  if (lane < nb) bsum[lane] = x - v;
  if (lane == 0) rowstart[NN] = EE;
}

__global__ __launch_bounds__(1024) void k_scan3(int* __restrict__ rowstart,
                                                const int* __restrict__ bsum) {
  int i = blockIdx.x * 1024 + threadIdx.x;
  if (i < NN) rowstart[i] += bsum[blockIdx.x];
}

// ---- CSR placement, atomic-free, ushort col ----
__global__ __launch_bounds__(256) void k_place(const int* __restrict__ src,
                                               const int* __restrict__ dst,
                                               const unsigned short* __restrict__ rank,
                                               const int* __restrict__ rowstart,
                                               unsigned short* __restrict__ col) {
  int e = blockIdx.x * 256 + threadIdx.x;
  if (e < EE) {
    int d = dst[e];
    col[rowstart[d] + (int)rank[e]] = (unsigned short)src[e];
  }
}

// ---- per-node logmap scales with dinv folded ----
__global__ __launch_bounds__(256) void k_scal(const float* __restrict__ xH,
                                              const float* __restrict__ xS,
                                              const float* __restrict__ dinv,
                                              float* __restrict__ sc1,
                                              float* __restrict__ sc2) {
  int gw = (blockIdx.x * 256 + threadIdx.x) >> 6;
  int lane = threadIdx.x & 63;
  if (gw >= NN) return;
  const float2* h2 = (const float2*)(xH) + (size_t)gw * 64;
  float2 vh = h2[lane];
  float ssh = vh.x * vh.x + vh.y * vh.y;
  if (lane == 0) ssh -= vh.x * vh.x;  // direct sum over x[1:]
#pragma unroll
  for (int off = 32; off; off >>= 1) ssh += __shfl_down(ssh, off);
  const float2* s2 = (const float2*)(xS) + (size_t)gw * 64;
  float2 vs = s2[lane];
  float sss = vs.x * vs.x + vs.y * vs.y;
  if (lane == 0) sss -= vs.x * vs.x;
#pragma unroll
  for (int off = 32; off; off >>= 1) sss += __shfl_down(sss, off);
  if (lane == 0) {
    float dv = dinv[gw];
    float nrh = sqrtf(ssh);
    float dist = acoshf(fmaxf(vh.x, 1.0f));
    sc1[gw] = dv * dist / fmaxf(nrh, 1e-12f);
    float nrs = sqrtf(sss);
    float th = acosf(fminf(fmaxf(vs.x, -1.0f), 1.0f));
    sc2[gw] = dv * th / fmaxf(nrs, 1e-12f);
  }
}

// ---- W transpose fp16 + normalized class embeddings, one launch ----
__global__ __launch_bounds__(256) void k_wcprep(const float* __restrict__ W,
                                                const float* __restrict__ cls,
                                                unsigned short* __restrict__ Wt,
                                                unsigned int* __restrict__ clsp) {
  int bid = blockIdx.x;
  if (bid < 192) {  // W transpose: 49152 elements
    int flat = bid * 256 + threadIdx.x;
    int n = flat / IND;
    int k = flat - n * IND;
    Wt[(size_t)n * IND + k] = f2h(W[(size_t)k * DD + n]);
  } else {  // class normalize (1 block)
    int wave = threadIdx.x >> 6, lane = threadIdx.x & 63;
    for (int c = wave; c < CC; c += 4) {
      const float2* r2 = (const float2*)(cls + (size_t)c * DD);
      float2 v = r2[lane];
      float ss = v.x * v.x + v.y * v.y;
#pragma unroll
      for (int off = 32; off; off >>= 1) ss += __shfl_xor(ss, off);
      float inv = 1.0f / fmaxf(sqrtf(ss), 1e-8f);
      clsp[c * 64 + lane] =
          (unsigned int)f2h(v.x * inv) | ((unsigned int)f2h(v.y * inv) << 16);
    }
  }
}

// ---- MFMA fp16 GEMM: h = dinv * ([xE | ch*xH | cs*xS] @ W), fp16 out ----
__global__ __launch_bounds__(256) void k_gemm(const float* __restrict__ xE,
                                              const float* __restrict__ xH,
                                              const float* __restrict__ xS,
                                              const float* __restrict__ dinv,
                                              const float* __restrict__ sc1,
                                              const float* __restrict__ sc2,
                                              const unsigned short* __restrict__ Wt,
                                              unsigned short* __restrict__ h) {
  __shared__ unsigned short Ah[64 * 64];  // 8 KB
  int tid = threadIdx.x;
  int lane = tid & 63;
  int wid = tid >> 6;
  int wr = wid >> 1, wc = wid & 1;
  int r0 = wr * 32, c0 = wc * 64;
  int bm0 = blockIdx.x * 64;
  int l15 = lane & 15;
  int lhi = lane >> 4;

  f4v acc[2][4];
#pragma unroll
  for (int m = 0; m < 2; ++m)
#pragma unroll
    for (int nf = 0; nf < 4; ++nf) acc[m][nf] = f4v{0.f, 0.f, 0.f, 0.f};

  for (int kb = 0; kb < IND; kb += 64) {
    int sec = kb >> 7;
    int off = kb & 127;
    const float* __restrict__ src = (sec == 0) ? xE : (sec == 1) ? xH : xS;
#pragma unroll
    for (int it = 0; it < 4; ++it) {
      int flat = tid + it * 256;
      int row = flat >> 4;
      int f4 = flat & 15;
      int node = bm0 + row;
      float4 v = make_float4(0.f, 0.f, 0.f, 0.f);
      float scale = 0.f;
      if (node < NN) {
        v = *(const float4*)&src[(size_t)node * DD + off + f4 * 4];
        scale = (sec == 0) ? dinv[node] : (sec == 1) ? sc1[node] : sc2[node];
      }
      v.x *= scale; v.y *= scale; v.z *= scale; v.w *= scale;
      if (sec > 0 && off == 0 && f4 == 0) v.x = 0.f;  // logmap zero column
      ushort4 o;
      o.x = f2h(v.x); o.y = f2h(v.y); o.z = f2h(v.z); o.w = f2h(v.w);
      int idx = (row * 64 + f4 * 4) ^ ((row & 7) << 3);
      *(ushort4*)&Ah[idx] = o;
    }
    __syncthreads();
#pragma unroll
    for (int ks = 0; ks < 2; ++ks) {
      h8v a[2];
#pragma unroll
      for (int m = 0; m < 2; ++m) {
        int row = r0 + m * 16 + l15;
        int idx = (row * 64 + ks * 32 + lhi * 8) ^ ((row & 7) << 3);
        a[m] = *reinterpret_cast<const h8v*>(&Ah[idx]);
      }
      int kk = kb + ks * 32 + lhi * 8;
#pragma unroll
      for (int nf = 0; nf < 4; ++nf) {
        int n = c0 + nf * 16 + l15;
        h8v b = *reinterpret_cast<const h8v*>(&Wt[(size_t)n * IND + kk]);
#pragma unroll
        for (int m = 0; m < 2; ++m)
          acc[m][nf] = __builtin_amdgcn_mfma_f32_16x16x32_f16(a[m], b, acc[m][nf], 0, 0, 0);
      }
    }
    __syncthreads();
  }
#pragma unroll
  for (int m = 0; m < 2; ++m)
#pragma unroll
    for (int nf = 0; nf < 4; ++nf) {
      int colx = c0 + nf * 16 + l15;
      int rowb = bm0 + r0 + m * 16 + lhi * 4;
#pragma unroll
      for (int j = 0; j < 4; ++j) {
        int node = rowb + j;
        if (node < NN) h[(size_t)node * DD + colx] = f2h(acc[m][nf][j]);
      }
    }
}

// ---- CSR aggregation (h pre-scaled by dinv) + normalize -> xn fp16 ----
__global__ __launch_bounds__(256) void k_aggn(const unsigned short* __restrict__ h,
                                              const int* __restrict__ rowstart,
                                              const unsigned short* __restrict__ col,
                                              const float* __restrict__ dinv,
                                              const float* __restrict__ b,
                                              unsigned int* __restrict__ xn) {
  int node = (blockIdx.x * 256 + threadIdx.x) >> 6;
  int lane = threadIdx.x & 63;
  if (node >= NN) return;

  const unsigned int* h2 = (const unsigned int*)h;
  float dv = dinv[node];
  unsigned int hv = h2[(size_t)node * 64 + lane];
  float ax = hlo(hv), ay = hhi(hv);
  int s = rowstart[node], e = rowstart[node + 1];
  int j = s;
  for (; j + 15 < e; j += 16) {
    int cc[16];
    unsigned int vv[16];
#pragma unroll
    for (int q = 0; q < 16; ++q) cc[q] = col[j + q];
#pragma unroll
    for (int q = 0; q < 16; ++q) vv[q] = h2[(size_t)cc[q] * 64 + lane];
#pragma unroll
    for (int q = 0; q < 16; ++q) {
      ax += hlo(vv[q]);
      ay += hhi(vv[q]);
    }
  }
  for (; j + 3 < e; j += 4) {
    int c0_ = col[j], c1_ = col[j + 1], c2_ = col[j + 2], c3_ = col[j + 3];
    unsigned int v0 = h2[(size_t)c0_ * 64 + lane];
    unsigned int v1 = h2[(size_t)c1_ * 64 + lane];
    unsigned int v2 = h2[(size_t)c2_ * 64 + lane];
    unsigned int v3 = h2[(size_t)c3_ * 64 + lane];
    ax += hlo(v0) + hlo(v1) + hlo(v2) + hlo(v3);
    ay += hhi(v0) + hhi(v1) + hhi(v2) + hhi(v3);
  }
  for (; j < e; ++j) {
    unsigned int v = h2[(size_t)col[j] * 64 + lane];
    ax += hlo(v);
    ay += hhi(v);
  }
  const float2* b2 = (const float2*)b;
  float2 bb = b2[lane];
  float rx = dv * ax + bb.x;
  float ry = dv * ay + bb.y;
  float ss = rx * rx + ry * ry;
#pragma unroll
  for (int off = 32; off; off >>= 1) ss += __shfl_xor(ss, off);
  float inv = 1.0f / fmaxf(sqrtf(ss), 1e-8f);
  xn[(size_t)node * 64 + lane] =
      (unsigned int)f2h(rx * inv) | ((unsigned int)f2h(ry * inv) << 16);
}

// ---- classifier fp16 MFMA GEMM: out = xn @ clsn^T ----
__global__ __launch_bounds__(256) void k_outg(const unsigned short* __restrict__ xn,
                                              const unsigned short* __restrict__ clsp,
                                              float* __restrict__ out) {
  int tid = threadIdx.x;
  int lane = tid & 63;
  int wid = tid >> 6;
  int l15 = lane & 15, lhi = lane >> 4;
  int bm0 = blockIdx.x * 128 + wid * 32;

  f4v acc[2][4];
#pragma unroll
  for (int m = 0; m < 2; ++m)
#pragma unroll
    for (int nf = 0; nf < 4; ++nf) acc[m][nf] = f4v{0.f, 0.f, 0.f, 0.f};

#pragma unroll
  for (int ks = 0; ks < 4; ++ks) {
    h8v a[2];
#pragma unroll
    for (int m = 0; m < 2; ++m) {
      int row = bm0 + m * 16 + l15;
      a[m] = (row < NN)
                 ? *reinterpret_cast<const h8v*>(&xn[(size_t)row * DD + ks * 32 + lhi * 8])
                 : hzero();
    }
#pragma unroll
    for (int nf = 0; nf < 4; ++nf) {
      int n = nf * 16 + l15;
      h8v b = *reinterpret_cast<const h8v*>(&clsp[(size_t)n * DD + ks * 32 + lhi * 8]);
#pragma unroll
      for (int m = 0; m < 2; ++m)
        acc[m][nf] = __builtin_amdgcn_mfma_f32_16x16x32_f16(a[m], b, acc[m][nf], 0, 0, 0);
    }
  }
#pragma unroll
  for (int m = 0; m < 2; ++m)
#pragma unroll
    for (int nf = 0; nf < 4; ++nf) {
      int colx = nf * 16 + l15;
      int rowb = bm0 + m * 16 + lhi * 4;
#pragma unroll
      for (int j = 0; j < 4; ++j) {
        int row = rowb + j;
        if (row < NN) out[(size_t)row * CC + colx] = acc[m][nf][j];
      }
    }
}

extern "C" void kernel_launch(void* const* d_in, const int* in_sizes, int n_in,
                              void* d_out, int out_size, void* d_ws, size_t ws_size,
                              hipStream_t stream) {
  const float* xE = (const float*)d_in[0];
  const float* xH = (const float*)d_in[1];
  const float* xS = (const float*)d_in[2];
  const int* ei = (const int*)d_in[3];
  const float* W = (const float*)d_in[4];
  const float* b = (const float*)d_in[5];
  const float* cls = (const float*)d_in[6];
  float* out = (float*)d_out;

  char* ws = (char*)d_ws;
  size_t off = 0;
  auto alloc = [&](size_t bytes) {
    void* p = ws + off;
    off = (off + bytes + 255) & ~(size_t)255;
    return p;
  };
  unsigned short* h = (unsigned short*)alloc((size_t)NN * DD * 2);
  unsigned int* xn = (unsigned int*)alloc((size_t)NN * 64 * 4);
  float* dinv = (float*)alloc((size_t)NN * 4);
  float* sc1 = (float*)alloc((size_t)NN * 4);
  float* sc2 = (float*)alloc((size_t)NN * 4);
  int* cnt = (int*)alloc((size_t)(NN + 16) * 4);
  int* rowst = (int*)alloc((size_t)(NN + 1) * 4);
  unsigned short* rank = (unsigned short*)alloc((size_t)EE * 2);
  unsigned short* col = (unsigned short*)alloc((size_t)EE * 2);
  unsigned short* Wt = (unsigned short*)alloc((size_t)DD * IND * 2);
  unsigned int* clsp = (unsigned int*)alloc((size_t)CC * 64 * 4);
  int* bsum = (int*)alloc(64 * 4);

  const int* esrc = ei;
  const int* edst = ei + EE;
  const int NB = (NN + 1023) / 1024;
  const int N4 = (NN + 3) / 4;

  k_zero<<<(N4 + 255) / 256, 256, 0, stream>>>((int4*)cnt, N4);
  k_count<<<(EE + 255) / 256, 256, 0, stream>>>(edst, cnt, rank);
  k_scan1<<<NB, 1024, 0, stream>>>(cnt, rowst, dinv, bsum);
  k_scan2<<<1, 64, 0, stream>>>(bsum, rowst, NB);
  k_scan3<<<NB, 1024, 0, stream>>>(rowst, bsum);
  k_place<<<(EE + 255) / 256, 256, 0, stream>>>(esrc, edst, rank, rowst, col);
  k_wcprep<<<193, 256, 0, stream>>>(W, cls, Wt, clsp);
  k_scal<<<(NN + 3) / 4, 256, 0, stream>>>(xH, xS, dinv, sc1, sc2);
  k_gemm<<<(NN + 63) / 64, 256, 0, stream>>>(xE, xH, xS, dinv, sc1, sc2, Wt, h);
  k_aggn<<<(NN + 3) / 4, 256, 0, stream>>>(h, rowst, col, dinv, b, xn);
  k_outg<<<(NN + 127) / 128, 256, 0, stream>>>((const unsigned short*)xn,
                                               (const unsigned short*)clsp, out);
}

// Round 14
// 165.220 us; speedup vs baseline: 1.2214x; 1.0189x over previous
//
#include <hip/hip_runtime.h>
#include <hip/hip_fp16.h>
#include <math.h>

#define NN 50000
#define DD 128
#define CC 64
#define EE 800000
#define IND 384

typedef __attribute__((ext_vector_type(8))) _Float16 h8v;
typedef __attribute__((ext_vector_type(4))) float f4v;

static __device__ __forceinline__ unsigned short f2h(float f) {
  _Float16 h = (_Float16)f;
  return *reinterpret_cast<unsigned short*>(&h);
}
static __device__ __forceinline__ float h2f(unsigned short u) {
  _Float16 h = *reinterpret_cast<_Float16*>(&u);
  return (float)h;
}
static __device__ __forceinline__ float hlo(unsigned int u) {
  return h2f((unsigned short)(u & 0xffffu));
}
static __device__ __forceinline__ float hhi(unsigned int u) {
  return h2f((unsigned short)(u >> 16));
}
static __device__ __forceinline__ h8v hzero() {
  h8v v = {0, 0, 0, 0, 0, 0, 0, 0};
  return v;
}

// ---- W transpose fp16 + class normalize + cnt zero, one launch ----
__global__ __launch_bounds__(256) void k_wcprep(const float* __restrict__ W,
                                                const float* __restrict__ cls,
                                                unsigned short* __restrict__ Wt,
                                                unsigned int* __restrict__ clsp,
                                                int4* __restrict__ cnt4, int n4) {
  int bid = blockIdx.x;
  if (bid < 192) {  // W transpose: 49152 elements
    int flat = bid * 256 + threadIdx.x;
    int n = flat / IND;
    int k = flat - n * IND;
    Wt[(size_t)n * IND + k] = f2h(W[(size_t)k * DD + n]);
  } else if (bid == 192) {  // class normalize (1 block)
    int wave = threadIdx.x >> 6, lane = threadIdx.x & 63;
    for (int c = wave; c < CC; c += 4) {
      const float2* r2 = (const float2*)(cls + (size_t)c * DD);
      float2 v = r2[lane];
      float ss = v.x * v.x + v.y * v.y;
#pragma unroll
      for (int off = 32; off; off >>= 1) ss += __shfl_xor(ss, off);
      float inv = 1.0f / fmaxf(sqrtf(ss), 1e-8f);
      clsp[c * 64 + lane] =
          (unsigned int)f2h(v.x * inv) | ((unsigned int)f2h(v.y * inv) << 16);
    }
  } else {  // zero cnt: blocks 193.. cover n4 int4s
    int i = (bid - 193) * 256 + threadIdx.x;
    if (i < n4) cnt4[i] = make_int4(0, 0, 0, 0);
  }
}

// ---- degree count + rank, 4 edges/thread (4 atomics in flight) ----
__global__ __launch_bounds__(256) void k_count(const int* __restrict__ dst,
                                               int* __restrict__ cnt,
                                               unsigned short* __restrict__ rank) {
  int t = blockIdx.x * 256 + threadIdx.x;
  int e = t * 4;
  if (e >= EE) return;
  int4 d = *(const int4*)&dst[e];
  unsigned short r0 = (unsigned short)atomicAdd(&cnt[d.x], 1);
  unsigned short r1 = (unsigned short)atomicAdd(&cnt[d.y], 1);
  unsigned short r2 = (unsigned short)atomicAdd(&cnt[d.z], 1);
  unsigned short r3 = (unsigned short)atomicAdd(&cnt[d.w], 1);
  ushort4 r;
  r.x = r0; r.y = r1; r.z = r2; r.w = r3;
  *(ushort4*)&rank[e] = r;
}

// ---------------- hierarchical exclusive scan ----------------
__global__ __launch_bounds__(1024) void k_scan1(const int* __restrict__ cnt,
                                                int* __restrict__ rowstart,
                                                float* __restrict__ dinv,
                                                int* __restrict__ bsum) {
  __shared__ int wsum[16];
  int tid = threadIdx.x;
  int wave = tid >> 6, lane = tid & 63;
  int i = blockIdx.x * 1024 + tid;
  int v = (i < NN) ? cnt[i] : 0;
  int x = v;
#pragma unroll
  for (int off = 1; off < 64; off <<= 1) {
    int t = __shfl_up(x, off);
    if (lane >= off) x += t;
  }
  if (lane == 63) wsum[wave] = x;
  __syncthreads();
  if (wave == 0 && lane < 16) {
    int y = wsum[lane];
#pragma unroll
    for (int off = 1; off < 16; off <<= 1) {
      int t = __shfl_up(y, off);
      if (lane >= off) y += t;
    }
    wsum[lane] = y;
  }
  __syncthreads();
  int ex = (wave ? wsum[wave - 1] : 0) + x - v;
  if (i < NN) {
    rowstart[i] = ex;
    dinv[i] = 1.0f / sqrtf((float)(v + 1));
  }
  if (tid == 1023) bsum[blockIdx.x] = wsum[15];
}

__global__ __launch_bounds__(64) void k_scan2(int* __restrict__ bsum,
                                              int* __restrict__ rowstart,
                                              int nb) {
  int lane = threadIdx.x;
  int v = (lane < nb) ? bsum[lane] : 0;
  int x = v;
#pragma unroll
  for (int off = 1; off < 64; off <<= 1) {
    int t = __shfl_up(x, off);
    if (lane >= off) x += t;
  }
  if (lane < nb) bsum[lane] = x - v;
  if (lane == 0) rowstart[NN] = EE;
}

__global__ __launch_bounds__(1024) void k_scan3(int* __restrict__ rowstart,
                                                const int* __restrict__ bsum) {
  int i = blockIdx.x * 1024 + threadIdx.x;
  if (i < NN) rowstart[i] += bsum[blockIdx.x];
}

// ---- CSR placement, atomic-free, 4 edges/thread ----
__global__ __launch_bounds__(256) void k_place(const int* __restrict__ src,
                                               const int* __restrict__ dst,
                                               const unsigned short* __restrict__ rank,
                                               const int* __restrict__ rowstart,
                                               unsigned short* __restrict__ col) {
  int t = blockIdx.x * 256 + threadIdx.x;
  int e = t * 4;
  if (e >= EE) return;
  int4 s = *(const int4*)&src[e];
  int4 d = *(const int4*)&dst[e];
  ushort4 r = *(const ushort4*)&rank[e];
  int p0 = rowstart[d.x] + (int)r.x;
  int p1 = rowstart[d.y] + (int)r.y;
  int p2 = rowstart[d.z] + (int)r.z;
  int p3 = rowstart[d.w] + (int)r.w;
  col[p0] = (unsigned short)s.x;
  col[p1] = (unsigned short)s.y;
  col[p2] = (unsigned short)s.z;
  col[p3] = (unsigned short)s.w;
}

// ---- per-node logmap scales with dinv folded ----
__global__ __launch_bounds__(256) void k_scal(const float* __restrict__ xH,
                                              const float* __restrict__ xS,
                                              const float* __restrict__ dinv,
                                              float* __restrict__ sc1,
                                              float* __restrict__ sc2) {
  int gw = (blockIdx.x * 256 + threadIdx.x) >> 6;
  int lane = threadIdx.x & 63;
  if (gw >= NN) return;
  const float2* h2 = (const float2*)(xH) + (size_t)gw * 64;
  float2 vh = h2[lane];
  float ssh = vh.x * vh.x + vh.y * vh.y;
  if (lane == 0) ssh -= vh.x * vh.x;  // direct sum over x[1:]
#pragma unroll
  for (int off = 32; off; off >>= 1) ssh += __shfl_down(ssh, off);
  const float2* s2 = (const float2*)(xS) + (size_t)gw * 64;
  float2 vs = s2[lane];
  float sss = vs.x * vs.x + vs.y * vs.y;
  if (lane == 0) sss -= vs.x * vs.x;
#pragma unroll
  for (int off = 32; off; off >>= 1) sss += __shfl_down(sss, off);
  if (lane == 0) {
    float dv = dinv[gw];
    float nrh = sqrtf(ssh);
    float dist = acoshf(fmaxf(vh.x, 1.0f));
    sc1[gw] = dv * dist / fmaxf(nrh, 1e-12f);
    float nrs = sqrtf(sss);
    float th = acosf(fminf(fmaxf(vs.x, -1.0f), 1.0f));
    sc2[gw] = dv * th / fmaxf(nrs, 1e-12f);
  }
}

// ---- MFMA fp16 GEMM: h = dinv * ([xE | ch*xH | cs*xS] @ W), fp16 out ----
__global__ __launch_bounds__(256) void k_gemm(const float* __restrict__ xE,
                                              const float* __restrict__ xH,
                                              const float* __restrict__ xS,
                                              const float* __restrict__ dinv,
                                              const float* __restrict__ sc1,
                                              const float* __restrict__ sc2,
                                              const unsigned short* __restrict__ Wt,
                                              unsigned short* __restrict__ h) {
  __shared__ unsigned short Ah[64 * 64];  // 8 KB
  int tid = threadIdx.x;
  int lane = tid & 63;
  int wid = tid >> 6;
  int wr = wid >> 1, wc = wid & 1;
  int r0 = wr * 32, c0 = wc * 64;
  int bm0 = blockIdx.x * 64;
  int l15 = lane & 15;
  int lhi = lane >> 4;

  f4v acc[2][4];
#pragma unroll
  for (int m = 0; m < 2; ++m)
#pragma unroll
    for (int nf = 0; nf < 4; ++nf) acc[m][nf] = f4v{0.f, 0.f, 0.f, 0.f};

  for (int kb = 0; kb < IND; kb += 64) {
    int sec = kb >> 7;
    int off = kb & 127;
    const float* __restrict__ src = (sec == 0) ? xE : (sec == 1) ? xH : xS;
#pragma unroll
    for (int it = 0; it < 4; ++it) {
      int flat = tid + it * 256;
      int row = flat >> 4;
      int f4 = flat & 15;
      int node = bm0 + row;
      float4 v = make_float4(0.f, 0.f, 0.f, 0.f);
      float scale = 0.f;
      if (node < NN) {
        v = *(const float4*)&src[(size_t)node * DD + off + f4 * 4];
        scale = (sec == 0) ? dinv[node] : (sec == 1) ? sc1[node] : sc2[node];
      }
      v.x *= scale; v.y *= scale; v.z *= scale; v.w *= scale;
      if (sec > 0 && off == 0 && f4 == 0) v.x = 0.f;  // logmap zero column
      ushort4 o;
      o.x = f2h(v.x); o.y = f2h(v.y); o.z = f2h(v.z); o.w = f2h(v.w);
      int idx = (row * 64 + f4 * 4) ^ ((row & 7) << 3);
      *(ushort4*)&Ah[idx] = o;
    }
    __syncthreads();
#pragma unroll
    for (int ks = 0; ks < 2; ++ks) {
      h8v a[2];
#pragma unroll
      for (int m = 0; m < 2; ++m) {
        int row = r0 + m * 16 + l15;
        int idx = (row * 64 + ks * 32 + lhi * 8) ^ ((row & 7) << 3);
        a[m] = *reinterpret_cast<const h8v*>(&Ah[idx]);
      }
      int kk = kb + ks * 32 + lhi * 8;
#pragma unroll
      for (int nf = 0; nf < 4; ++nf) {
        int n = c0 + nf * 16 + l15;
        h8v b = *reinterpret_cast<const h8v*>(&Wt[(size_t)n * IND + kk]);
#pragma unroll
        for (int m = 0; m < 2; ++m)
          acc[m][nf] = __builtin_amdgcn_mfma_f32_16x16x32_f16(a[m], b, acc[m][nf], 0, 0, 0);
      }
    }
    __syncthreads();
  }
#pragma unroll
  for (int m = 0; m < 2; ++m)
#pragma unroll
    for (int nf = 0; nf < 4; ++nf) {
      int colx = c0 + nf * 16 + l15;
      int rowb = bm0 + r0 + m * 16 + lhi * 4;
#pragma unroll
      for (int j = 0; j < 4; ++j) {
        int node = rowb + j;
        if (node < NN) h[(size_t)node * DD + colx] = f2h(acc[m][nf][j]);
      }
    }
}

// ---- CSR aggregation (h pre-scaled by dinv) + normalize -> xn fp16 ----
__global__ __launch_bounds__(256) void k_aggn(const unsigned short* __restrict__ h,
                                              const int* __restrict__ rowstart,
                                              const unsigned short* __restrict__ col,
                                              const float* __restrict__ dinv,
                                              const float* __restrict__ b,
                                              unsigned int* __restrict__ xn) {
  int node = (blockIdx.x * 256 + threadIdx.x) >> 6;
  int lane = threadIdx.x & 63;
  if (node >= NN) return;

  const unsigned int* h2 = (const unsigned int*)h;
  float dv = dinv[node];
  unsigned int hv = h2[(size_t)node * 64 + lane];
  float ax = hlo(hv), ay = hhi(hv);
  int s = rowstart[node], e = rowstart[node + 1];
  int j = s;
  for (; j + 15 < e; j += 16) {
    int cc[16];
    unsigned int vv[16];
#pragma unroll
    for (int q = 0; q < 16; ++q) cc[q] = col[j + q];
#pragma unroll
    for (int q = 0; q < 16; ++q) vv[q] = h2[(size_t)cc[q] * 64 + lane];
#pragma unroll
    for (int q = 0; q < 16; ++q) {
      ax += hlo(vv[q]);
      ay += hhi(vv[q]);
    }
  }
  for (; j + 3 < e; j += 4) {
    int c0_ = col[j], c1_ = col[j + 1], c2_ = col[j + 2], c3_ = col[j + 3];
    unsigned int v0 = h2[(size_t)c0_ * 64 + lane];
    unsigned int v1 = h2[(size_t)c1_ * 64 + lane];
    unsigned int v2 = h2[(size_t)c2_ * 64 + lane];
    unsigned int v3 = h2[(size_t)c3_ * 64 + lane];
    ax += hlo(v0) + hlo(v1) + hlo(v2) + hlo(v3);
    ay += hhi(v0) + hhi(v1) + hhi(v2) + hhi(v3);
  }
  for (; j < e; ++j) {
    unsigned int v = h2[(size_t)col[j] * 64 + lane];
    ax += hlo(v);
    ay += hhi(v);
  }
  const float2* b2 = (const float2*)b;
  float2 bb = b2[lane];
  float rx = dv * ax + bb.x;
  float ry = dv * ay + bb.y;
  float ss = rx * rx + ry * ry;
#pragma unroll
  for (int off = 32; off; off >>= 1) ss += __shfl_xor(ss, off);
  float inv = 1.0f / fmaxf(sqrtf(ss), 1e-8f);
  xn[(size_t)node * 64 + lane] =
      (unsigned int)f2h(rx * inv) | ((unsigned int)f2h(ry * inv) << 16);
}

// ---- classifier fp16 MFMA GEMM: out = xn @ clsn^T ----
__global__ __launch_bounds__(256) void k_outg(const unsigned short* __restrict__ xn,
                                              const unsigned short* __restrict__ clsp,
                                              float* __restrict__ out) {
  int tid = threadIdx.x;
  int lane = tid & 63;
  int wid = tid >> 6;
  int l15 = lane & 15, lhi = lane >> 4;
  int bm0 = blockIdx.x * 128 + wid * 32;

  f4v acc[2][4];
#pragma unroll
  for (int m = 0; m < 2; ++m)
#pragma unroll
    for (int nf = 0; nf < 4; ++nf) acc[m][nf] = f4v{0.f, 0.f, 0.f, 0.f};

#pragma unroll
  for (int ks = 0; ks < 4; ++ks) {
    h8v a[2];
#pragma unroll
    for (int m = 0; m < 2; ++m) {
      int row = bm0 + m * 16 + l15;
      a[m] = (row < NN)
                 ? *reinterpret_cast<const h8v*>(&xn[(size_t)row * DD + ks * 32 + lhi * 8])
                 : hzero();
    }
#pragma unroll
    for (int nf = 0; nf < 4; ++nf) {
      int n = nf * 16 + l15;
      h8v b = *reinterpret_cast<const h8v*>(&clsp[(size_t)n * DD + ks * 32 + lhi * 8]);
#pragma unroll
      for (int m = 0; m < 2; ++m)
        acc[m][nf] = __builtin_amdgcn_mfma_f32_16x16x32_f16(a[m], b, acc[m][nf], 0, 0, 0);
    }
  }
#pragma unroll
  for (int m = 0; m < 2; ++m)
#pragma unroll
    for (int nf = 0; nf < 4; ++nf) {
      int colx = nf * 16 + l15;
      int rowb = bm0 + m * 16 + lhi * 4;
#pragma unroll
      for (int j = 0; j < 4; ++j) {
        int row = rowb + j;
        if (row < NN) out[(size_t)row * CC + colx] = acc[m][nf][j];
      }
    }
}

extern "C" void kernel_launch(void* const* d_in, const int* in_sizes, int n_in,
                              void* d_out, int out_size, void* d_ws, size_t ws_size,
                              hipStream_t stream) {
  const float* xE = (const float*)d_in[0];
  const float* xH = (const float*)d_in[1];
  const float* xS = (const float*)d_in[2];
  const int* ei = (const int*)d_in[3];
  const float* W = (const float*)d_in[4];
  const float* b = (const float*)d_in[5];
  const float* cls = (const float*)d_in[6];
  float* out = (float*)d_out;

  char* ws = (char*)d_ws;
  size_t off = 0;
  auto alloc = [&](size_t bytes) {
    void* p = ws + off;
    off = (off + bytes + 255) & ~(size_t)255;
    return p;
  };
  unsigned short* h = (unsigned short*)alloc((size_t)NN * DD * 2);
  unsigned int* xn = (unsigned int*)alloc((size_t)NN * 64 * 4);
  float* dinv = (float*)alloc((size_t)NN * 4);
  float* sc1 = (float*)alloc((size_t)NN * 4);
  float* sc2 = (float*)alloc((size_t)NN * 4);
  int* cnt = (int*)alloc((size_t)(NN + 16) * 4);
  int* rowst = (int*)alloc((size_t)(NN + 1) * 4);
  unsigned short* rank = (unsigned short*)alloc((size_t)EE * 2);
  unsigned short* col = (unsigned short*)alloc((size_t)EE * 2);
  unsigned short* Wt = (unsigned short*)alloc((size_t)DD * IND * 2);
  unsigned int* clsp = (unsigned int*)alloc((size_t)CC * 64 * 4);
  int* bsum = (int*)alloc(64 * 4);

  const int* esrc = ei;
  const int* edst = ei + EE;
  const int NB = (NN + 1023) / 1024;
  const int N4 = (NN + 3) / 4;                 // 12500 int4s
  const int ZB = (N4 + 255) / 256;             // 49 zero blocks

  k_wcprep<<<193 + ZB, 256, 0, stream>>>(W, cls, Wt, clsp, (int4*)cnt, N4);
  k_count<<<(EE / 4 + 255) / 256, 256, 0, stream>>>(edst, cnt, rank);
  k_scan1<<<NB, 1024, 0, stream>>>(cnt, rowst, dinv, bsum);
  k_scan2<<<1, 64, 0, stream>>>(bsum, rowst, NB);
  k_scan3<<<NB, 1024, 0, stream>>>(rowst, bsum);
  k_place<<<(EE / 4 + 255) / 256, 256, 0, stream>>>(esrc, edst, rank, rowst, col);
  k_scal<<<(NN + 3) / 4, 256, 0, stream>>>(xH, xS, dinv, sc1, sc2);
  k_gemm<<<(NN + 63) / 64, 256, 0, stream>>>(xE, xH, xS, dinv, sc1, sc2, Wt, h);
  k_aggn<<<(NN + 3) / 4, 256, 0, stream>>>(h, rowst, col, dinv, b, xn);
  k_outg<<<(NN + 127) / 128, 256, 0, stream>>>((const unsigned short*)xn,
                                               (const unsigned short*)clsp, out);
}

// Round 15
// 160.013 us; speedup vs baseline: 1.2611x; 1.0325x over previous
//
#include <hip/hip_runtime.h>
#include <hip/hip_fp16.h>
#include <math.h>

#define NN 50000
#define DD 128
#define CC 64
#define EE 800000
#define IND 384

typedef __attribute__((ext_vector_type(8))) _Float16 h8v;
typedef __attribute__((ext_vector_type(4))) float f4v;

static __device__ __forceinline__ unsigned short f2h(float f) {
  _Float16 h = (_Float16)f;
  return *reinterpret_cast<unsigned short*>(&h);
}
static __device__ __forceinline__ float h2f(unsigned short u) {
  _Float16 h = *reinterpret_cast<_Float16*>(&u);
  return (float)h;
}
static __device__ __forceinline__ float hlo(unsigned int u) {
  return h2f((unsigned short)(u & 0xffffu));
}
static __device__ __forceinline__ float hhi(unsigned int u) {
  return h2f((unsigned short)(u >> 16));
}
static __device__ __forceinline__ h8v hzero() {
  h8v v = {0, 0, 0, 0, 0, 0, 0, 0};
  return v;
}

// ---- fused prep: logmap scales (raw, no dinv) + W transpose + class norm
//      + cnt zero, one launch. Scal blocks first (long pole). ----
#define SCAL_B 12500   // NN/4 nodes, wave-per-node
#define WT_B   192     // 49152 W elements
__global__ __launch_bounds__(256) void k_prep(const float* __restrict__ W,
                                              const float* __restrict__ cls,
                                              const float* __restrict__ xH,
                                              const float* __restrict__ xS,
                                              unsigned short* __restrict__ Wt,
                                              unsigned int* __restrict__ clsp,
                                              float* __restrict__ ch,
                                              float* __restrict__ cs,
                                              int4* __restrict__ cnt4, int n4) {
  int bid = blockIdx.x;
  if (bid < SCAL_B) {  // logmap scales: raw ch, cs (dinv folded later in gemm)
    int gw = bid * 4 + (threadIdx.x >> 6);
    int lane = threadIdx.x & 63;
    const float2* h2 = (const float2*)(xH) + (size_t)gw * 64;
    float2 vh = h2[lane];
    float ssh = vh.x * vh.x + vh.y * vh.y;
    if (lane == 0) ssh -= vh.x * vh.x;  // direct sum over x[1:]
#pragma unroll
    for (int off = 32; off; off >>= 1) ssh += __shfl_down(ssh, off);
    const float2* s2 = (const float2*)(xS) + (size_t)gw * 64;
    float2 vs = s2[lane];
    float sss = vs.x * vs.x + vs.y * vs.y;
    if (lane == 0) sss -= vs.x * vs.x;
#pragma unroll
    for (int off = 32; off; off >>= 1) sss += __shfl_down(sss, off);
    if (lane == 0) {
      float nrh = sqrtf(ssh);
      float dist = acoshf(fmaxf(vh.x, 1.0f));
      ch[gw] = dist / fmaxf(nrh, 1e-12f);
      float nrs = sqrtf(sss);
      float th = acosf(fminf(fmaxf(vs.x, -1.0f), 1.0f));
      cs[gw] = th / fmaxf(nrs, 1e-12f);
    }
  } else if (bid < SCAL_B + WT_B) {  // W transpose fp16
    int flat = (bid - SCAL_B) * 256 + threadIdx.x;
    int n = flat / IND;
    int k = flat - n * IND;
    Wt[(size_t)n * IND + k] = f2h(W[(size_t)k * DD + n]);
  } else if (bid == SCAL_B + WT_B) {  // class normalize
    int wave = threadIdx.x >> 6, lane = threadIdx.x & 63;
    for (int c = wave; c < CC; c += 4) {
      const float2* r2 = (const float2*)(cls + (size_t)c * DD);
      float2 v = r2[lane];
      float ss = v.x * v.x + v.y * v.y;
#pragma unroll
      for (int off = 32; off; off >>= 1) ss += __shfl_xor(ss, off);
      float inv = 1.0f / fmaxf(sqrtf(ss), 1e-8f);
      clsp[c * 64 + lane] =
          (unsigned int)f2h(v.x * inv) | ((unsigned int)f2h(v.y * inv) << 16);
    }
  } else {  // zero cnt
    int i = (bid - (SCAL_B + WT_B + 1)) * 256 + threadIdx.x;
    if (i < n4) cnt4[i] = make_int4(0, 0, 0, 0);
  }
}

// ---- degree count + rank, 4 edges/thread ----
__global__ __launch_bounds__(256) void k_count(const int* __restrict__ dst,
                                               int* __restrict__ cnt,
                                               unsigned short* __restrict__ rank) {
  int t = blockIdx.x * 256 + threadIdx.x;
  int e = t * 4;
  if (e >= EE) return;
  int4 d = *(const int4*)&dst[e];
  unsigned short r0 = (unsigned short)atomicAdd(&cnt[d.x], 1);
  unsigned short r1 = (unsigned short)atomicAdd(&cnt[d.y], 1);
  unsigned short r2 = (unsigned short)atomicAdd(&cnt[d.z], 1);
  unsigned short r3 = (unsigned short)atomicAdd(&cnt[d.w], 1);
  ushort4 r;
  r.x = r0; r.y = r1; r.z = r2; r.w = r3;
  *(ushort4*)&rank[e] = r;
}

// ---------------- hierarchical exclusive scan ----------------
__global__ __launch_bounds__(1024) void k_scan1(const int* __restrict__ cnt,
                                                int* __restrict__ rowstart,
                                                float* __restrict__ dinv,
                                                int* __restrict__ bsum) {
  __shared__ int wsum[16];
  int tid = threadIdx.x;
  int wave = tid >> 6, lane = tid & 63;
  int i = blockIdx.x * 1024 + tid;
  int v = (i < NN) ? cnt[i] : 0;
  int x = v;
#pragma unroll
  for (int off = 1; off < 64; off <<= 1) {
    int t = __shfl_up(x, off);
    if (lane >= off) x += t;
  }
  if (lane == 63) wsum[wave] = x;
  __syncthreads();
  if (wave == 0 && lane < 16) {
    int y = wsum[lane];
#pragma unroll
    for (int off = 1; off < 16; off <<= 1) {
      int t = __shfl_up(y, off);
      if (lane >= off) y += t;
    }
    wsum[lane] = y;
  }
  __syncthreads();
  int ex = (wave ? wsum[wave - 1] : 0) + x - v;
  if (i < NN) {
    rowstart[i] = ex;
    dinv[i] = 1.0f / sqrtf((float)(v + 1));
  }
  if (tid == 1023) bsum[blockIdx.x] = wsum[15];
}

__global__ __launch_bounds__(64) void k_scan2(int* __restrict__ bsum,
                                              int* __restrict__ rowstart,
                                              int nb) {
  int lane = threadIdx.x;
  int v = (lane < nb) ? bsum[lane] : 0;
  int x = v;
#pragma unroll
  for (int off = 1; off < 64; off <<= 1) {
    int t = __shfl_up(x, off);
    if (lane >= off) x += t;
  }
  if (lane < nb) bsum[lane] = x - v;
  if (lane == 0) rowstart[NN] = EE;
}

__global__ __launch_bounds__(1024) void k_scan3(int* __restrict__ rowstart,
                                                const int* __restrict__ bsum) {
  int i = blockIdx.x * 1024 + threadIdx.x;
  if (i < NN) rowstart[i] += bsum[blockIdx.x];
}

// ---- CSR placement, atomic-free, 4 edges/thread ----
__global__ __launch_bounds__(256) void k_place(const int* __restrict__ src,
                                               const int* __restrict__ dst,
                                               const unsigned short* __restrict__ rank,
                                               const int* __restrict__ rowstart,
                                               unsigned short* __restrict__ col) {
  int t = blockIdx.x * 256 + threadIdx.x;
  int e = t * 4;
  if (e >= EE) return;
  int4 s = *(const int4*)&src[e];
  int4 d = *(const int4*)&dst[e];
  ushort4 r = *(const ushort4*)&rank[e];
  int p0 = rowstart[d.x] + (int)r.x;
  int p1 = rowstart[d.y] + (int)r.y;
  int p2 = rowstart[d.z] + (int)r.z;
  int p3 = rowstart[d.w] + (int)r.w;
  col[p0] = (unsigned short)s.x;
  col[p1] = (unsigned short)s.y;
  col[p2] = (unsigned short)s.z;
  col[p3] = (unsigned short)s.w;
}

// ---- MFMA fp16 GEMM: h = dinv * ([xE | ch*xH | cs*xS] @ W), fp16 out ----
__global__ __launch_bounds__(256) void k_gemm(const float* __restrict__ xE,
                                              const float* __restrict__ xH,
                                              const float* __restrict__ xS,
                                              const float* __restrict__ dinv,
                                              const float* __restrict__ ch,
                                              const float* __restrict__ cs,
                                              const unsigned short* __restrict__ Wt,
                                              unsigned short* __restrict__ h) {
  __shared__ unsigned short Ah[64 * 64];  // 8 KB
  int tid = threadIdx.x;
  int lane = tid & 63;
  int wid = tid >> 6;
  int wr = wid >> 1, wc = wid & 1;
  int r0 = wr * 32, c0 = wc * 64;
  int bm0 = blockIdx.x * 64;
  int l15 = lane & 15;
  int lhi = lane >> 4;

  f4v acc[2][4];
#pragma unroll
  for (int m = 0; m < 2; ++m)
#pragma unroll
    for (int nf = 0; nf < 4; ++nf) acc[m][nf] = f4v{0.f, 0.f, 0.f, 0.f};

  for (int kb = 0; kb < IND; kb += 64) {
    int sec = kb >> 7;
    int off = kb & 127;
    const float* __restrict__ src = (sec == 0) ? xE : (sec == 1) ? xH : xS;
#pragma unroll
    for (int it = 0; it < 4; ++it) {
      int flat = tid + it * 256;
      int row = flat >> 4;
      int f4 = flat & 15;
      int node = bm0 + row;
      float4 v = make_float4(0.f, 0.f, 0.f, 0.f);
      float scale = 0.f;
      if (node < NN) {
        v = *(const float4*)&src[(size_t)node * DD + off + f4 * 4];
        float dvn = dinv[node];
        scale = (sec == 0) ? dvn : (sec == 1) ? ch[node] * dvn : cs[node] * dvn;
      }
      v.x *= scale; v.y *= scale; v.z *= scale; v.w *= scale;
      if (sec > 0 && off == 0 && f4 == 0) v.x = 0.f;  // logmap zero column
      ushort4 o;
      o.x = f2h(v.x); o.y = f2h(v.y); o.z = f2h(v.z); o.w = f2h(v.w);
      int idx = (row * 64 + f4 * 4) ^ ((row & 7) << 3);
      *(ushort4*)&Ah[idx] = o;
    }
    __syncthreads();
#pragma unroll
    for (int ks = 0; ks < 2; ++ks) {
      h8v a[2];
#pragma unroll
      for (int m = 0; m < 2; ++m) {
        int row = r0 + m * 16 + l15;
        int idx = (row * 64 + ks * 32 + lhi * 8) ^ ((row & 7) << 3);
        a[m] = *reinterpret_cast<const h8v*>(&Ah[idx]);
      }
      int kk = kb + ks * 32 + lhi * 8;
#pragma unroll
      for (int nf = 0; nf < 4; ++nf) {
        int n = c0 + nf * 16 + l15;
        h8v b = *reinterpret_cast<const h8v*>(&Wt[(size_t)n * IND + kk]);
#pragma unroll
        for (int m = 0; m < 2; ++m)
          acc[m][nf] = __builtin_amdgcn_mfma_f32_16x16x32_f16(a[m], b, acc[m][nf], 0, 0, 0);
      }
    }
    __syncthreads();
  }
#pragma unroll
  for (int m = 0; m < 2; ++m)
#pragma unroll
    for (int nf = 0; nf < 4; ++nf) {
      int colx = c0 + nf * 16 + l15;
      int rowb = bm0 + r0 + m * 16 + lhi * 4;
#pragma unroll
      for (int j = 0; j < 4; ++j) {
        int node = rowb + j;
        if (node < NN) h[(size_t)node * DD + colx] = f2h(acc[m][nf][j]);
      }
    }
}

// ---- CSR aggregation, 2 nodes/wave (32 lanes x uint2 each) -> xn fp16 ----
// 32 independent row-gathers in flight per wave (double MLP vs 1-node/wave).
__global__ __launch_bounds__(256) void k_aggn(const unsigned short* __restrict__ h,
                                              const int* __restrict__ rowstart,
                                              const unsigned short* __restrict__ col,
                                              const float* __restrict__ dinv,
                                              const float* __restrict__ b,
                                              unsigned int* __restrict__ xn) {
  int tid = threadIdx.x;
  int wave = tid >> 6;
  int hl = (tid >> 5) & 1;   // half-wave = node slot
  int li = tid & 31;         // lane within half-wave
  int node = blockIdx.x * 8 + wave * 2 + hl;  // 6250 blocks * 8 = 50000 exact
  if (node >= NN) return;

  const uint2* h2 = (const uint2*)h;  // row = 32 uint2 = 256 B
  float dv = dinv[node];
  uint2 hv = h2[(size_t)node * 32 + li];
  float a0 = hlo(hv.x), a1 = hhi(hv.x), a2 = hlo(hv.y), a3 = hhi(hv.y);
  int s = rowstart[node], e = rowstart[node + 1];
  int j = s;
  for (; j + 15 < e; j += 16) {
    int cc[16];
    uint2 vv[16];
#pragma unroll
    for (int q = 0; q < 16; ++q) cc[q] = col[j + q];
#pragma unroll
    for (int q = 0; q < 16; ++q) vv[q] = h2[(size_t)cc[q] * 32 + li];
#pragma unroll
    for (int q = 0; q < 16; ++q) {
      a0 += hlo(vv[q].x);
      a1 += hhi(vv[q].x);
      a2 += hlo(vv[q].y);
      a3 += hhi(vv[q].y);
    }
  }
  for (; j + 3 < e; j += 4) {
    int c0_ = col[j], c1_ = col[j + 1], c2_ = col[j + 2], c3_ = col[j + 3];
    uint2 v0 = h2[(size_t)c0_ * 32 + li];
    uint2 v1 = h2[(size_t)c1_ * 32 + li];
    uint2 v2 = h2[(size_t)c2_ * 32 + li];
    uint2 v3 = h2[(size_t)c3_ * 32 + li];
    a0 += hlo(v0.x) + hlo(v1.x) + hlo(v2.x) + hlo(v3.x);
    a1 += hhi(v0.x) + hhi(v1.x) + hhi(v2.x) + hhi(v3.x);
    a2 += hlo(v0.y) + hlo(v1.y) + hlo(v2.y) + hlo(v3.y);
    a3 += hhi(v0.y) + hhi(v1.y) + hhi(v2.y) + hhi(v3.y);
  }
  for (; j < e; ++j) {
    uint2 v = h2[(size_t)col[j] * 32 + li];
    a0 += hlo(v.x);
    a1 += hhi(v.x);
    a2 += hlo(v.y);
    a3 += hhi(v.y);
  }
  float4 bb = ((const float4*)b)[li];  // dims 4li..4li+3
  float r0 = dv * a0 + bb.x;
  float r1 = dv * a1 + bb.y;
  float r2 = dv * a2 + bb.z;
  float r3 = dv * a3 + bb.w;
  float ss = r0 * r0 + r1 * r1 + r2 * r2 + r3 * r3;
#pragma unroll
  for (int off = 16; off; off >>= 1) ss += __shfl_xor(ss, off);  // 32-lane reduce
  float inv = 1.0f / fmaxf(sqrtf(ss), 1e-8f);
  uint2 o;
  o.x = (unsigned int)f2h(r0 * inv) | ((unsigned int)f2h(r1 * inv) << 16);
  o.y = (unsigned int)f2h(r2 * inv) | ((unsigned int)f2h(r3 * inv) << 16);
  ((uint2*)xn)[(size_t)node * 32 + li] = o;
}

// ---- classifier fp16 MFMA GEMM: out = xn @ clsn^T ----
__global__ __launch_bounds__(256) void k_outg(const unsigned short* __restrict__ xn,
                                              const unsigned short* __restrict__ clsp,
                                              float* __restrict__ out) {
  int tid = threadIdx.x;
  int lane = tid & 63;
  int wid = tid >> 6;
  int l15 = lane & 15, lhi = lane >> 4;
  int bm0 = blockIdx.x * 128 + wid * 32;

  f4v acc[2][4];
#pragma unroll
  for (int m = 0; m < 2; ++m)
#pragma unroll
    for (int nf = 0; nf < 4; ++nf) acc[m][nf] = f4v{0.f, 0.f, 0.f, 0.f};

#pragma unroll
  for (int ks = 0; ks < 4; ++ks) {
    h8v a[2];
#pragma unroll
    for (int m = 0; m < 2; ++m) {
      int row = bm0 + m * 16 + l15;
      a[m] = (row < NN)
                 ? *reinterpret_cast<const h8v*>(&xn[(size_t)row * DD + ks * 32 + lhi * 8])
                 : hzero();
    }
#pragma unroll
    for (int nf = 0; nf < 4; ++nf) {
      int n = nf * 16 + l15;
      h8v b = *reinterpret_cast<const h8v*>(&clsp[(size_t)n * DD + ks * 32 + lhi * 8]);
#pragma unroll
      for (int m = 0; m < 2; ++m)
        acc[m][nf] = __builtin_amdgcn_mfma_f32_16x16x32_f16(a[m], b, acc[m][nf], 0, 0, 0);
    }
  }
#pragma unroll
  for (int m = 0; m < 2; ++m)
#pragma unroll
    for (int nf = 0; nf < 4; ++nf) {
      int colx = nf * 16 + l15;
      int rowb = bm0 + m * 16 + lhi * 4;
#pragma unroll
      for (int j = 0; j < 4; ++j) {
        int row = rowb + j;
        if (row < NN) out[(size_t)row * CC + colx] = acc[m][nf][j];
      }
    }
}

extern "C" void kernel_launch(void* const* d_in, const int* in_sizes, int n_in,
                              void* d_out, int out_size, void* d_ws, size_t ws_size,
                              hipStream_t stream) {
  const float* xE = (const float*)d_in[0];
  const float* xH = (const float*)d_in[1];
  const float* xS = (const float*)d_in[2];
  const int* ei = (const int*)d_in[3];
  const float* W = (const float*)d_in[4];
  const float* b = (const float*)d_in[5];
  const float* cls = (const float*)d_in[6];
  float* out = (float*)d_out;

  char* ws = (char*)d_ws;
  size_t off = 0;
  auto alloc = [&](size_t bytes) {
    void* p = ws + off;
    off = (off + bytes + 255) & ~(size_t)255;
    return p;
  };
  unsigned short* h = (unsigned short*)alloc((size_t)NN * DD * 2);
  unsigned int* xn = (unsigned int*)alloc((size_t)NN * 64 * 4);
  float* dinv = (float*)alloc((size_t)NN * 4);
  float* chv = (float*)alloc((size_t)NN * 4);
  float* csv = (float*)alloc((size_t)NN * 4);
  int* cnt = (int*)alloc((size_t)(NN + 16) * 4);
  int* rowst = (int*)alloc((size_t)(NN + 1) * 4);
  unsigned short* rank = (unsigned short*)alloc((size_t)EE * 2);
  unsigned short* col = (unsigned short*)alloc((size_t)EE * 2);
  unsigned short* Wt = (unsigned short*)alloc((size_t)DD * IND * 2);
  unsigned int* clsp = (unsigned int*)alloc((size_t)CC * 64 * 4);
  int* bsum = (int*)alloc(64 * 4);

  const int* esrc = ei;
  const int* edst = ei + EE;
  const int NB = (NN + 1023) / 1024;
  const int N4 = (NN + 3) / 4;                 // 12500 int4s
  const int ZB = (N4 + 255) / 256;             // 49 zero blocks

  k_prep<<<SCAL_B + WT_B + 1 + ZB, 256, 0, stream>>>(W, cls, xH, xS, Wt, clsp,
                                                     chv, csv, (int4*)cnt, N4);
  k_count<<<(EE / 4 + 255) / 256, 256, 0, stream>>>(edst, cnt, rank);
  k_scan1<<<NB, 1024, 0, stream>>>(cnt, rowst, dinv, bsum);
  k_scan2<<<1, 64, 0, stream>>>(bsum, rowst, NB);
  k_scan3<<<NB, 1024, 0, stream>>>(rowst, bsum);
  k_place<<<(EE / 4 + 255) / 256, 256, 0, stream>>>(esrc, edst, rank, rowst, col);
  k_gemm<<<(NN + 63) / 64, 256, 0, stream>>>(xE, xH, xS, dinv, chv, csv, Wt, h);
  k_aggn<<<(NN + 7) / 8, 256, 0, stream>>>(h, rowst, col, dinv, b, xn);
  k_outg<<<(NN + 127) / 128, 256, 0, stream>>>((const unsigned short*)xn,
                                               (const unsigned short*)clsp, out);
}

// Round 16
// 156.203 us; speedup vs baseline: 1.2919x; 1.0244x over previous
//
#include <hip/hip_runtime.h>
#include <hip/hip_fp16.h>
#include <math.h>

#define NN 50000
#define DD 128
#define CC 64
#define EE 800000
#define IND 384

typedef __attribute__((ext_vector_type(8))) _Float16 h8v;
typedef __attribute__((ext_vector_type(4))) float f4v;

static __device__ __forceinline__ unsigned short f2h(float f) {
  _Float16 h = (_Float16)f;
  return *reinterpret_cast<unsigned short*>(&h);
}
static __device__ __forceinline__ float h2f(unsigned short u) {
  _Float16 h = *reinterpret_cast<_Float16*>(&u);
  return (float)h;
}
static __device__ __forceinline__ float hlo(unsigned int u) {
  return h2f((unsigned short)(u & 0xffffu));
}
static __device__ __forceinline__ float hhi(unsigned int u) {
  return h2f((unsigned short)(u >> 16));
}
static __device__ __forceinline__ h8v hzero() {
  h8v v = {0, 0, 0, 0, 0, 0, 0, 0};
  return v;
}

// ---- fused prep: logmap scales (raw) + W transpose + class norm + cnt zero ----
#define SCAL_B 12500   // NN/4 nodes, wave-per-node
#define WT_B   192     // 49152 W elements
__global__ __launch_bounds__(256) void k_prep(const float* __restrict__ W,
                                              const float* __restrict__ cls,
                                              const float* __restrict__ xH,
                                              const float* __restrict__ xS,
                                              unsigned short* __restrict__ Wt,
                                              unsigned int* __restrict__ clsp,
                                              float* __restrict__ ch,
                                              float* __restrict__ cs,
                                              int4* __restrict__ cnt4, int n4) {
  int bid = blockIdx.x;
  if (bid < SCAL_B) {  // logmap scales: raw ch, cs (dinv folded in scan3)
    int gw = bid * 4 + (threadIdx.x >> 6);
    int lane = threadIdx.x & 63;
    const float2* h2 = (const float2*)(xH) + (size_t)gw * 64;
    float2 vh = h2[lane];
    float ssh = vh.x * vh.x + vh.y * vh.y;
    if (lane == 0) ssh -= vh.x * vh.x;  // direct sum over x[1:]
#pragma unroll
    for (int off = 32; off; off >>= 1) ssh += __shfl_down(ssh, off);
    const float2* s2 = (const float2*)(xS) + (size_t)gw * 64;
    float2 vs = s2[lane];
    float sss = vs.x * vs.x + vs.y * vs.y;
    if (lane == 0) sss -= vs.x * vs.x;
#pragma unroll
    for (int off = 32; off; off >>= 1) sss += __shfl_down(sss, off);
    if (lane == 0) {
      float nrh = sqrtf(ssh);
      float dist = acoshf(fmaxf(vh.x, 1.0f));
      ch[gw] = dist / fmaxf(nrh, 1e-12f);
      float nrs = sqrtf(sss);
      float th = acosf(fminf(fmaxf(vs.x, -1.0f), 1.0f));
      cs[gw] = th / fmaxf(nrs, 1e-12f);
    }
  } else if (bid < SCAL_B + WT_B) {  // W transpose fp16
    int flat = (bid - SCAL_B) * 256 + threadIdx.x;
    int n = flat / IND;
    int k = flat - n * IND;
    Wt[(size_t)n * IND + k] = f2h(W[(size_t)k * DD + n]);
  } else if (bid == SCAL_B + WT_B) {  // class normalize
    int wave = threadIdx.x >> 6, lane = threadIdx.x & 63;
    for (int c = wave; c < CC; c += 4) {
      const float2* r2 = (const float2*)(cls + (size_t)c * DD);
      float2 v = r2[lane];
      float ss = v.x * v.x + v.y * v.y;
#pragma unroll
      for (int off = 32; off; off >>= 1) ss += __shfl_xor(ss, off);
      float inv = 1.0f / fmaxf(sqrtf(ss), 1e-8f);
      clsp[c * 64 + lane] =
          (unsigned int)f2h(v.x * inv) | ((unsigned int)f2h(v.y * inv) << 16);
    }
  } else {  // zero cnt
    int i = (bid - (SCAL_B + WT_B + 1)) * 256 + threadIdx.x;
    if (i < n4) cnt4[i] = make_int4(0, 0, 0, 0);
  }
}

// ---- degree count + rank, 4 edges/thread ----
__global__ __launch_bounds__(256) void k_count(const int* __restrict__ dst,
                                               int* __restrict__ cnt,
                                               unsigned short* __restrict__ rank) {
  int t = blockIdx.x * 256 + threadIdx.x;
  int e = t * 4;
  if (e >= EE) return;
  int4 d = *(const int4*)&dst[e];
  unsigned short r0 = (unsigned short)atomicAdd(&cnt[d.x], 1);
  unsigned short r1 = (unsigned short)atomicAdd(&cnt[d.y], 1);
  unsigned short r2 = (unsigned short)atomicAdd(&cnt[d.z], 1);
  unsigned short r3 = (unsigned short)atomicAdd(&cnt[d.w], 1);
  ushort4 r;
  r.x = r0; r.y = r1; r.z = r2; r.w = r3;
  *(ushort4*)&rank[e] = r;
}

// ---------------- hierarchical exclusive scan ----------------
__global__ __launch_bounds__(1024) void k_scan1(const int* __restrict__ cnt,
                                                int* __restrict__ rowstart,
                                                float* __restrict__ dinv,
                                                int* __restrict__ bsum) {
  __shared__ int wsum[16];
  int tid = threadIdx.x;
  int wave = tid >> 6, lane = tid & 63;
  int i = blockIdx.x * 1024 + tid;
  int v = (i < NN) ? cnt[i] : 0;
  int x = v;
#pragma unroll
  for (int off = 1; off < 64; off <<= 1) {
    int t = __shfl_up(x, off);
    if (lane >= off) x += t;
  }
  if (lane == 63) wsum[wave] = x;
  __syncthreads();
  if (wave == 0 && lane < 16) {
    int y = wsum[lane];
#pragma unroll
    for (int off = 1; off < 16; off <<= 1) {
      int t = __shfl_up(y, off);
      if (lane >= off) y += t;
    }
    wsum[lane] = y;
  }
  __syncthreads();
  int ex = (wave ? wsum[wave - 1] : 0) + x - v;
  if (i < NN) {
    rowstart[i] = ex;
    dinv[i] = 1.0f / sqrtf((float)(v + 1));
  }
  if (tid == 1023) bsum[blockIdx.x] = wsum[15];
}

__global__ __launch_bounds__(64) void k_scan2(int* __restrict__ bsum,
                                              int* __restrict__ rowstart,
                                              int nb) {
  int lane = threadIdx.x;
  int v = (lane < nb) ? bsum[lane] : 0;
  int x = v;
#pragma unroll
  for (int off = 1; off < 64; off <<= 1) {
    int t = __shfl_up(x, off);
    if (lane >= off) x += t;
  }
  if (lane < nb) bsum[lane] = x - v;
  if (lane == 0) rowstart[NN] = EE;
}

// ---- scan3: finalize rowstart AND fold dinv into ch/cs (in-place) ----
__global__ __launch_bounds__(1024) void k_scan3(int* __restrict__ rowstart,
                                                const int* __restrict__ bsum,
                                                const float* __restrict__ dinv,
                                                float* __restrict__ ch,
                                                float* __restrict__ cs) {
  int i = blockIdx.x * 1024 + threadIdx.x;
  if (i < NN) {
    rowstart[i] += bsum[blockIdx.x];
    float dv = dinv[i];
    ch[i] *= dv;
    cs[i] *= dv;
  }
}

// ---- CSR placement, atomic-free, 4 edges/thread ----
__global__ __launch_bounds__(256) void k_place(const int* __restrict__ src,
                                               const int* __restrict__ dst,
                                               const unsigned short* __restrict__ rank,
                                               const int* __restrict__ rowstart,
                                               unsigned short* __restrict__ col) {
  int t = blockIdx.x * 256 + threadIdx.x;
  int e = t * 4;
  if (e >= EE) return;
  int4 s = *(const int4*)&src[e];
  int4 d = *(const int4*)&dst[e];
  ushort4 r = *(const ushort4*)&rank[e];
  int p0 = rowstart[d.x] + (int)r.x;
  int p1 = rowstart[d.y] + (int)r.y;
  int p2 = rowstart[d.z] + (int)r.z;
  int p3 = rowstart[d.w] + (int)r.w;
  col[p0] = (unsigned short)s.x;
  col[p1] = (unsigned short)s.y;
  col[p2] = (unsigned short)s.z;
  col[p3] = (unsigned short)s.w;
}

// ---- MFMA fp16 GEMM: 32 rows x 128 cols per block, 4 waves of 32r x 32c ----
// 1563 blocks (~6/CU, ~24 waves/CU) vs old 782. Same total MFMA/load work.
__global__ __launch_bounds__(256) void k_gemm(const float* __restrict__ xE,
                                              const float* __restrict__ xH,
                                              const float* __restrict__ xS,
                                              const float* __restrict__ dinv,
                                              const float* __restrict__ sc1,
                                              const float* __restrict__ sc2,
                                              const unsigned short* __restrict__ Wt,
                                              unsigned short* __restrict__ h) {
  __shared__ unsigned short Ah[32 * 64];  // 4 KB
  int tid = threadIdx.x;
  int lane = tid & 63;
  int wid = tid >> 6;
  int c0 = wid * 32;
  int bm0 = blockIdx.x * 32;
  int l15 = lane & 15;
  int lhi = lane >> 4;

  f4v acc[2][2];
#pragma unroll
  for (int m = 0; m < 2; ++m)
#pragma unroll
    for (int nf = 0; nf < 2; ++nf) acc[m][nf] = f4v{0.f, 0.f, 0.f, 0.f};

  for (int kb = 0; kb < IND; kb += 64) {
    int sec = kb >> 7;
    int off = kb & 127;
    const float* __restrict__ src = (sec == 0) ? xE : (sec == 1) ? xH : xS;
#pragma unroll
    for (int it = 0; it < 2; ++it) {
      int flat = tid + it * 256;
      int row = flat >> 4;       // 0..31
      int f4 = flat & 15;
      int node = bm0 + row;
      float4 v = make_float4(0.f, 0.f, 0.f, 0.f);
      float scale = 0.f;
      if (node < NN) {
        v = *(const float4*)&src[(size_t)node * DD + off + f4 * 4];
        scale = (sec == 0) ? dinv[node] : (sec == 1) ? sc1[node] : sc2[node];
      }
      v.x *= scale; v.y *= scale; v.z *= scale; v.w *= scale;
      if (sec > 0 && off == 0 && f4 == 0) v.x = 0.f;  // logmap zero column
      ushort4 o;
      o.x = f2h(v.x); o.y = f2h(v.y); o.z = f2h(v.z); o.w = f2h(v.w);
      int idx = (row * 64 + f4 * 4) ^ ((row & 7) << 3);
      *(ushort4*)&Ah[idx] = o;
    }
    __syncthreads();
#pragma unroll
    for (int ks = 0; ks < 2; ++ks) {
      h8v a[2];
#pragma unroll
      for (int m = 0; m < 2; ++m) {
        int row = m * 16 + l15;
        int idx = (row * 64 + ks * 32 + lhi * 8) ^ ((row & 7) << 3);
        a[m] = *reinterpret_cast<const h8v*>(&Ah[idx]);
      }
      int kk = kb + ks * 32 + lhi * 8;
#pragma unroll
      for (int nf = 0; nf < 2; ++nf) {
        int n = c0 + nf * 16 + l15;
        h8v b = *reinterpret_cast<const h8v*>(&Wt[(size_t)n * IND + kk]);
#pragma unroll
        for (int m = 0; m < 2; ++m)
          acc[m][nf] = __builtin_amdgcn_mfma_f32_16x16x32_f16(a[m], b, acc[m][nf], 0, 0, 0);
      }
    }
    __syncthreads();
  }
#pragma unroll
  for (int m = 0; m < 2; ++m)
#pragma unroll
    for (int nf = 0; nf < 2; ++nf) {
      int colx = c0 + nf * 16 + l15;
      int rowb = bm0 + m * 16 + lhi * 4;
#pragma unroll
      for (int j = 0; j < 4; ++j) {
        int node = rowb + j;
        if (node < NN) h[(size_t)node * DD + colx] = f2h(acc[m][nf][j]);
      }
    }
}

// ---- CSR aggregation, 2 nodes/wave (32 lanes x uint2 each) -> xn fp16 ----
__global__ __launch_bounds__(256) void k_aggn(const unsigned short* __restrict__ h,
                                              const int* __restrict__ rowstart,
                                              const unsigned short* __restrict__ col,
                                              const float* __restrict__ dinv,
                                              const float* __restrict__ b,
                                              unsigned int* __restrict__ xn) {
  int tid = threadIdx.x;
  int wave = tid >> 6;
  int hl = (tid >> 5) & 1;
  int li = tid & 31;
  int node = blockIdx.x * 8 + wave * 2 + hl;
  if (node >= NN) return;

  const uint2* h2 = (const uint2*)h;
  float dv = dinv[node];
  uint2 hv = h2[(size_t)node * 32 + li];
  float a0 = hlo(hv.x), a1 = hhi(hv.x), a2 = hlo(hv.y), a3 = hhi(hv.y);
  int s = rowstart[node], e = rowstart[node + 1];
  int j = s;
  for (; j + 15 < e; j += 16) {
    int cc[16];
    uint2 vv[16];
#pragma unroll
    for (int q = 0; q < 16; ++q) cc[q] = col[j + q];
#pragma unroll
    for (int q = 0; q < 16; ++q) vv[q] = h2[(size_t)cc[q] * 32 + li];
#pragma unroll
    for (int q = 0; q < 16; ++q) {
      a0 += hlo(vv[q].x);
      a1 += hhi(vv[q].x);
      a2 += hlo(vv[q].y);
      a3 += hhi(vv[q].y);
    }
  }
  for (; j + 3 < e; j += 4) {
    int c0_ = col[j], c1_ = col[j + 1], c2_ = col[j + 2], c3_ = col[j + 3];
    uint2 v0 = h2[(size_t)c0_ * 32 + li];
    uint2 v1 = h2[(size_t)c1_ * 32 + li];
    uint2 v2 = h2[(size_t)c2_ * 32 + li];
    uint2 v3 = h2[(size_t)c3_ * 32 + li];
    a0 += hlo(v0.x) + hlo(v1.x) + hlo(v2.x) + hlo(v3.x);
    a1 += hhi(v0.x) + hhi(v1.x) + hhi(v2.x) + hhi(v3.x);
    a2 += hlo(v0.y) + hlo(v1.y) + hlo(v2.y) + hlo(v3.y);
    a3 += hhi(v0.y) + hhi(v1.y) + hhi(v2.y) + hhi(v3.y);
  }
  for (; j < e; ++j) {
    uint2 v = h2[(size_t)col[j] * 32 + li];
    a0 += hlo(v.x);
    a1 += hhi(v.x);
    a2 += hlo(v.y);
    a3 += hhi(v.y);
  }
  float4 bb = ((const float4*)b)[li];
  float r0 = dv * a0 + bb.x;
  float r1 = dv * a1 + bb.y;
  float r2 = dv * a2 + bb.z;
  float r3 = dv * a3 + bb.w;
  float ss = r0 * r0 + r1 * r1 + r2 * r2 + r3 * r3;
#pragma unroll
  for (int off = 16; off; off >>= 1) ss += __shfl_xor(ss, off);
  float inv = 1.0f / fmaxf(sqrtf(ss), 1e-8f);
  uint2 o;
  o.x = (unsigned int)f2h(r0 * inv) | ((unsigned int)f2h(r1 * inv) << 16);
  o.y = (unsigned int)f2h(r2 * inv) | ((unsigned int)f2h(r3 * inv) << 16);
  ((uint2*)xn)[(size_t)node * 32 + li] = o;
}

// ---- classifier fp16 MFMA GEMM: out = xn @ clsn^T ----
__global__ __launch_bounds__(256) void k_outg(const unsigned short* __restrict__ xn,
                                              const unsigned short* __restrict__ clsp,
                                              float* __restrict__ out) {
  int tid = threadIdx.x;
  int lane = tid & 63;
  int wid = tid >> 6;
  int l15 = lane & 15, lhi = lane >> 4;
  int bm0 = blockIdx.x * 128 + wid * 32;

  f4v acc[2][4];
#pragma unroll
  for (int m = 0; m < 2; ++m)
#pragma unroll
    for (int nf = 0; nf < 4; ++nf) acc[m][nf] = f4v{0.f, 0.f, 0.f, 0.f};

#pragma unroll
  for (int ks = 0; ks < 4; ++ks) {
    h8v a[2];
#pragma unroll
    for (int m = 0; m < 2; ++m) {
      int row = bm0 + m * 16 + l15;
      a[m] = (row < NN)
                 ? *reinterpret_cast<const h8v*>(&xn[(size_t)row * DD + ks * 32 + lhi * 8])
                 : hzero();
    }
#pragma unroll
    for (int nf = 0; nf < 4; ++nf) {
      int n = nf * 16 + l15;
      h8v b = *reinterpret_cast<const h8v*>(&clsp[(size_t)n * DD + ks * 32 + lhi * 8]);
#pragma unroll
      for (int m = 0; m < 2; ++m)
        acc[m][nf] = __builtin_amdgcn_mfma_f32_16x16x32_f16(a[m], b, acc[m][nf], 0, 0, 0);
    }
  }
#pragma unroll
  for (int m = 0; m < 2; ++m)
#pragma unroll
    for (int nf = 0; nf < 4; ++nf) {
      int colx = nf * 16 + l15;
      int rowb = bm0 + m * 16 + lhi * 4;
#pragma unroll
      for (int j = 0; j < 4; ++j) {
        int row = rowb + j;
        if (row < NN) out[(size_t)row * CC + colx] = acc[m][nf][j];
      }
    }
}

extern "C" void kernel_launch(void* const* d_in, const int* in_sizes, int n_in,
                              void* d_out, int out_size, void* d_ws, size_t ws_size,
                              hipStream_t stream) {
  const float* xE = (const float*)d_in[0];
  const float* xH = (const float*)d_in[1];
  const float* xS = (const float*)d_in[2];
  const int* ei = (const int*)d_in[3];
  const float* W = (const float*)d_in[4];
  const float* b = (const float*)d_in[5];
  const float* cls = (const float*)d_in[6];
  float* out = (float*)d_out;

  char* ws = (char*)d_ws;
  size_t off = 0;
  auto alloc = [&](size_t bytes) {
    void* p = ws + off;
    off = (off + bytes + 255) & ~(size_t)255;
    return p;
  };
  unsigned short* h = (unsigned short*)alloc((size_t)NN * DD * 2);
  unsigned int* xn = (unsigned int*)alloc((size_t)NN * 64 * 4);
  float* dinv = (float*)alloc((size_t)NN * 4);
  float* chv = (float*)alloc((size_t)NN * 4);
  float* csv = (float*)alloc((size_t)NN * 4);
  int* cnt = (int*)alloc((size_t)(NN + 16) * 4);
  int* rowst = (int*)alloc((size_t)(NN + 1) * 4);
  unsigned short* rank = (unsigned short*)alloc((size_t)EE * 2);
  unsigned short* col = (unsigned short*)alloc((size_t)EE * 2);
  unsigned short* Wt = (unsigned short*)alloc((size_t)DD * IND * 2);
  unsigned int* clsp = (unsigned int*)alloc((size_t)CC * 64 * 4);
  int* bsum = (int*)alloc(64 * 4);

  const int* esrc = ei;
  const int* edst = ei + EE;
  const int NB = (NN + 1023) / 1024;
  const int N4 = (NN + 3) / 4;
  const int ZB = (N4 + 255) / 256;

  k_prep<<<SCAL_B + WT_B + 1 + ZB, 256, 0, stream>>>(W, cls, xH, xS, Wt, clsp,
                                                     chv, csv, (int4*)cnt, N4);
  k_count<<<(EE / 4 + 255) / 256, 256, 0, stream>>>(edst, cnt, rank);
  k_scan1<<<NB, 1024, 0, stream>>>(cnt, rowst, dinv, bsum);
  k_scan2<<<1, 64, 0, stream>>>(bsum, rowst, NB);
  k_scan3<<<NB, 1024, 0, stream>>>(rowst, bsum, dinv, chv, csv);
  k_place<<<(EE / 4 + 255) / 256, 256, 0, stream>>>(esrc, edst, rank, rowst, col);
  k_gemm<<<(NN + 31) / 32, 256, 0, stream>>>(xE, xH, xS, dinv, chv, csv, Wt, h);
  k_aggn<<<(NN + 7) / 8, 256, 0, stream>>>(h, rowst, col, dinv, b, xn);
  k_outg<<<(NN + 127) / 128, 256, 0, stream>>>((const unsigned short*)xn,
                                               (const unsigned short*)clsp, out);
}

// Round 17
// 153.872 us; speedup vs baseline: 1.3114x; 1.0152x over previous
//
#include <hip/hip_runtime.h>
#include <hip/hip_fp16.h>
#include <math.h>

#define NN 50000
#define DD 128
#define CC 64
#define EE 800000
#define IND 384

typedef __attribute__((ext_vector_type(8))) _Float16 h8v;
typedef __attribute__((ext_vector_type(4))) float f4v;

static __device__ __forceinline__ unsigned short f2h(float f) {
  _Float16 h = (_Float16)f;
  return *reinterpret_cast<unsigned short*>(&h);
}
static __device__ __forceinline__ float h2f(unsigned short u) {
  _Float16 h = *reinterpret_cast<_Float16*>(&u);
  return (float)h;
}
static __device__ __forceinline__ float hlo(unsigned int u) {
  return h2f((unsigned short)(u & 0xffffu));
}
static __device__ __forceinline__ float hhi(unsigned int u) {
  return h2f((unsigned short)(u >> 16));
}
static __device__ __forceinline__ h8v hzero() {
  h8v v = {0, 0, 0, 0, 0, 0, 0, 0};
  return v;
}

// ---- fused prep: logmap scales (raw) + W transpose + class norm + cnt zero ----
#define SCAL_B 12500   // NN/4 nodes, wave-per-node
#define WT_B   192     // 49152 W elements
__global__ __launch_bounds__(256) void k_prep(const float* __restrict__ W,
                                              const float* __restrict__ cls,
                                              const float* __restrict__ xH,
                                              const float* __restrict__ xS,
                                              unsigned short* __restrict__ Wt,
                                              unsigned int* __restrict__ clsp,
                                              float* __restrict__ ch,
                                              float* __restrict__ cs,
                                              int4* __restrict__ cnt4, int n4) {
  int bid = blockIdx.x;
  if (bid < SCAL_B) {  // logmap scales: raw ch, cs (dinv folded in scan3)
    int gw = bid * 4 + (threadIdx.x >> 6);
    int lane = threadIdx.x & 63;
    const float2* h2 = (const float2*)(xH) + (size_t)gw * 64;
    float2 vh = h2[lane];
    float ssh = vh.x * vh.x + vh.y * vh.y;
    if (lane == 0) ssh -= vh.x * vh.x;  // direct sum over x[1:]
#pragma unroll
    for (int off = 32; off; off >>= 1) ssh += __shfl_down(ssh, off);
    const float2* s2 = (const float2*)(xS) + (size_t)gw * 64;
    float2 vs = s2[lane];
    float sss = vs.x * vs.x + vs.y * vs.y;
    if (lane == 0) sss -= vs.x * vs.x;
#pragma unroll
    for (int off = 32; off; off >>= 1) sss += __shfl_down(sss, off);
    if (lane == 0) {
      float nrh = sqrtf(ssh);
      float dist = acoshf(fmaxf(vh.x, 1.0f));
      ch[gw] = dist / fmaxf(nrh, 1e-12f);
      float nrs = sqrtf(sss);
      float th = acosf(fminf(fmaxf(vs.x, -1.0f), 1.0f));
      cs[gw] = th / fmaxf(nrs, 1e-12f);
    }
  } else if (bid < SCAL_B + WT_B) {  // W transpose fp16
    int flat = (bid - SCAL_B) * 256 + threadIdx.x;
    int n = flat / IND;
    int k = flat - n * IND;
    Wt[(size_t)n * IND + k] = f2h(W[(size_t)k * DD + n]);
  } else if (bid == SCAL_B + WT_B) {  // class normalize
    int wave = threadIdx.x >> 6, lane = threadIdx.x & 63;
    for (int c = wave; c < CC; c += 4) {
      const float2* r2 = (const float2*)(cls + (size_t)c * DD);
      float2 v = r2[lane];
      float ss = v.x * v.x + v.y * v.y;
#pragma unroll
      for (int off = 32; off; off >>= 1) ss += __shfl_xor(ss, off);
      float inv = 1.0f / fmaxf(sqrtf(ss), 1e-8f);
      clsp[c * 64 + lane] =
          (unsigned int)f2h(v.x * inv) | ((unsigned int)f2h(v.y * inv) << 16);
    }
  } else {  // zero cnt
    int i = (bid - (SCAL_B + WT_B + 1)) * 256 + threadIdx.x;
    if (i < n4) cnt4[i] = make_int4(0, 0, 0, 0);
  }
}

// ---- degree count + rank, 4 edges/thread ----
__global__ __launch_bounds__(256) void k_count(const int* __restrict__ dst,
                                               int* __restrict__ cnt,
                                               unsigned short* __restrict__ rank) {
  int t = blockIdx.x * 256 + threadIdx.x;
  int e = t * 4;
  if (e >= EE) return;
  int4 d = *(const int4*)&dst[e];
  unsigned short r0 = (unsigned short)atomicAdd(&cnt[d.x], 1);
  unsigned short r1 = (unsigned short)atomicAdd(&cnt[d.y], 1);
  unsigned short r2 = (unsigned short)atomicAdd(&cnt[d.z], 1);
  unsigned short r3 = (unsigned short)atomicAdd(&cnt[d.w], 1);
  ushort4 r;
  r.x = r0; r.y = r1; r.z = r2; r.w = r3;
  *(ushort4*)&rank[e] = r;
}

// ---------------- scan1: per-block sums + dinv ----------------
__global__ __launch_bounds__(1024) void k_scan1(const int* __restrict__ cnt,
                                                int* __restrict__ rowstart,
                                                float* __restrict__ dinv,
                                                int* __restrict__ bsum) {
  __shared__ int wsum[16];
  int tid = threadIdx.x;
  int wave = tid >> 6, lane = tid & 63;
  int i = blockIdx.x * 1024 + tid;
  int v = (i < NN) ? cnt[i] : 0;
  int x = v;
#pragma unroll
  for (int off = 1; off < 64; off <<= 1) {
    int t = __shfl_up(x, off);
    if (lane >= off) x += t;
  }
  if (lane == 63) wsum[wave] = x;
  __syncthreads();
  if (wave == 0 && lane < 16) {
    int y = wsum[lane];
#pragma unroll
    for (int off = 1; off < 16; off <<= 1) {
      int t = __shfl_up(y, off);
      if (lane >= off) y += t;
    }
    wsum[lane] = y;
  }
  __syncthreads();
  int ex = (wave ? wsum[wave - 1] : 0) + x - v;
  if (i < NN) {
    rowstart[i] = ex;
    dinv[i] = 1.0f / sqrtf((float)(v + 1));
  }
  if (tid == 1023) bsum[blockIdx.x] = wsum[15];
}

// ---- scan3: inline block-offset scan (absorbs old scan2) + finalize rowstart
//      + fold dinv into ch/cs ----
__global__ __launch_bounds__(1024) void k_scan3(int* __restrict__ rowstart,
                                                const int* __restrict__ bsum,
                                                int nb,
                                                const float* __restrict__ dinv,
                                                float* __restrict__ ch,
                                                float* __restrict__ cs) {
  __shared__ int off_s;
  int tid = threadIdx.x;
  if (tid < 64) {
    int lane = tid;
    int v = (lane < nb) ? bsum[lane] : 0;
    int x = v;
#pragma unroll
    for (int off = 1; off < 64; off <<= 1) {
      int t = __shfl_up(x, off);
      if (lane >= off) x += t;
    }
    if (lane == (int)blockIdx.x) off_s = x - v;  // exclusive prefix for this block
  }
  __syncthreads();
  int i = blockIdx.x * 1024 + tid;
  if (i < NN) {
    rowstart[i] += off_s;
    float dv = dinv[i];
    ch[i] *= dv;
    cs[i] *= dv;
  }
  if (blockIdx.x == 0 && tid == 0) rowstart[NN] = EE;
}

// ---- CSR placement, atomic-free, 4 edges/thread ----
__global__ __launch_bounds__(256) void k_place(const int* __restrict__ src,
                                               const int* __restrict__ dst,
                                               const unsigned short* __restrict__ rank,
                                               const int* __restrict__ rowstart,
                                               unsigned short* __restrict__ col) {
  int t = blockIdx.x * 256 + threadIdx.x;
  int e = t * 4;
  if (e >= EE) return;
  int4 s = *(const int4*)&src[e];
  int4 d = *(const int4*)&dst[e];
  ushort4 r = *(const ushort4*)&rank[e];
  int p0 = rowstart[d.x] + (int)r.x;
  int p1 = rowstart[d.y] + (int)r.y;
  int p2 = rowstart[d.z] + (int)r.z;
  int p3 = rowstart[d.w] + (int)r.w;
  col[p0] = (unsigned short)s.x;
  col[p1] = (unsigned short)s.y;
  col[p2] = (unsigned short)s.z;
  col[p3] = (unsigned short)s.w;
}

// ---- MFMA fp16 GEMM: 32 rows x 128 cols per block, 4 waves of 32r x 32c ----
__global__ __launch_bounds__(256) void k_gemm(const float* __restrict__ xE,
                                              const float* __restrict__ xH,
                                              const float* __restrict__ xS,
                                              const float* __restrict__ dinv,
                                              const float* __restrict__ sc1,
                                              const float* __restrict__ sc2,
                                              const unsigned short* __restrict__ Wt,
                                              unsigned short* __restrict__ h) {
  __shared__ unsigned short Ah[32 * 64];  // 4 KB
  int tid = threadIdx.x;
  int lane = tid & 63;
  int wid = tid >> 6;
  int c0 = wid * 32;
  int bm0 = blockIdx.x * 32;
  int l15 = lane & 15;
  int lhi = lane >> 4;

  f4v acc[2][2];
#pragma unroll
  for (int m = 0; m < 2; ++m)
#pragma unroll
    for (int nf = 0; nf < 2; ++nf) acc[m][nf] = f4v{0.f, 0.f, 0.f, 0.f};

  for (int kb = 0; kb < IND; kb += 64) {
    int sec = kb >> 7;
    int off = kb & 127;
    const float* __restrict__ src = (sec == 0) ? xE : (sec == 1) ? xH : xS;
#pragma unroll
    for (int it = 0; it < 2; ++it) {
      int flat = tid + it * 256;
      int row = flat >> 4;       // 0..31
      int f4 = flat & 15;
      int node = bm0 + row;
      float4 v = make_float4(0.f, 0.f, 0.f, 0.f);
      float scale = 0.f;
      if (node < NN) {
        v = *(const float4*)&src[(size_t)node * DD + off + f4 * 4];
        scale = (sec == 0) ? dinv[node] : (sec == 1) ? sc1[node] : sc2[node];
      }
      v.x *= scale; v.y *= scale; v.z *= scale; v.w *= scale;
      if (sec > 0 && off == 0 && f4 == 0) v.x = 0.f;  // logmap zero column
      ushort4 o;
      o.x = f2h(v.x); o.y = f2h(v.y); o.z = f2h(v.z); o.w = f2h(v.w);
      int idx = (row * 64 + f4 * 4) ^ ((row & 7) << 3);
      *(ushort4*)&Ah[idx] = o;
    }
    __syncthreads();
#pragma unroll
    for (int ks = 0; ks < 2; ++ks) {
      h8v a[2];
#pragma unroll
      for (int m = 0; m < 2; ++m) {
        int row = m * 16 + l15;
        int idx = (row * 64 + ks * 32 + lhi * 8) ^ ((row & 7) << 3);
        a[m] = *reinterpret_cast<const h8v*>(&Ah[idx]);
      }
      int kk = kb + ks * 32 + lhi * 8;
#pragma unroll
      for (int nf = 0; nf < 2; ++nf) {
        int n = c0 + nf * 16 + l15;
        h8v b = *reinterpret_cast<const h8v*>(&Wt[(size_t)n * IND + kk]);
#pragma unroll
        for (int m = 0; m < 2; ++m)
          acc[m][nf] = __builtin_amdgcn_mfma_f32_16x16x32_f16(a[m], b, acc[m][nf], 0, 0, 0);
      }
    }
    __syncthreads();
  }
#pragma unroll
  for (int m = 0; m < 2; ++m)
#pragma unroll
    for (int nf = 0; nf < 2; ++nf) {
      int colx = c0 + nf * 16 + l15;
      int rowb = bm0 + m * 16 + lhi * 4;
#pragma unroll
      for (int j = 0; j < 4; ++j) {
        int node = rowb + j;
        if (node < NN) h[(size_t)node * DD + colx] = f2h(acc[m][nf][j]);
      }
    }
}

// ---- CSR aggregation, 4 nodes/wave (16 lanes x uint4 each) -> xn fp16 ----
// Row read = 16 lanes x 16B (one dwordx4/lane): half the VMEM instructions of
// the 32-lane/uint2 version, 64 distinct rows in flight per wave.
__global__ __launch_bounds__(256) void k_aggn(const unsigned short* __restrict__ h,
                                              const int* __restrict__ rowstart,
                                              const unsigned short* __restrict__ col,
                                              const float* __restrict__ dinv,
                                              const float* __restrict__ b,
                                              unsigned int* __restrict__ xn) {
  int tid = threadIdx.x;
  int wave = tid >> 6;
  int slot = (tid >> 4) & 3;   // node slot within wave
  int li = tid & 15;           // lane within 16-lane group
  int node = blockIdx.x * 16 + wave * 4 + slot;  // 3125 blocks * 16 = 50000 exact

  const uint4* h4 = (const uint4*)h;  // row = 16 uint4 = 256 B
  float dv = dinv[node];
  uint4 hv = h4[(size_t)node * 16 + li];
  float a0 = hlo(hv.x), a1 = hhi(hv.x), a2 = hlo(hv.y), a3 = hhi(hv.y);
  float a4 = hlo(hv.z), a5 = hhi(hv.z), a6 = hlo(hv.w), a7 = hhi(hv.w);
  int s = rowstart[node], e = rowstart[node + 1];
  int j = s;
  for (; j + 15 < e; j += 16) {
    int cc[16];
    uint4 vv[16];
#pragma unroll
    for (int q = 0; q < 16; ++q) cc[q] = col[j + q];
#pragma unroll
    for (int q = 0; q < 16; ++q) vv[q] = h4[(size_t)cc[q] * 16 + li];
#pragma unroll
    for (int q = 0; q < 16; ++q) {
      a0 += hlo(vv[q].x);
      a1 += hhi(vv[q].x);
      a2 += hlo(vv[q].y);
      a3 += hhi(vv[q].y);
      a4 += hlo(vv[q].z);
      a5 += hhi(vv[q].z);
      a6 += hlo(vv[q].w);
      a7 += hhi(vv[q].w);
    }
  }
  for (; j + 3 < e; j += 4) {
    int c0_ = col[j], c1_ = col[j + 1], c2_ = col[j + 2], c3_ = col[j + 3];
    uint4 v0 = h4[(size_t)c0_ * 16 + li];
    uint4 v1 = h4[(size_t)c1_ * 16 + li];
    uint4 v2 = h4[(size_t)c2_ * 16 + li];
    uint4 v3 = h4[(size_t)c3_ * 16 + li];
    a0 += hlo(v0.x) + hlo(v1.x) + hlo(v2.x) + hlo(v3.x);
    a1 += hhi(v0.x) + hhi(v1.x) + hhi(v2.x) + hhi(v3.x);
    a2 += hlo(v0.y) + hlo(v1.y) + hlo(v2.y) + hlo(v3.y);
    a3 += hhi(v0.y) + hhi(v1.y) + hhi(v2.y) + hhi(v3.y);
    a4 += hlo(v0.z) + hlo(v1.z) + hlo(v2.z) + hlo(v3.z);
    a5 += hhi(v0.z) + hhi(v1.z) + hhi(v2.z) + hhi(v3.z);
    a6 += hlo(v0.w) + hlo(v1.w) + hlo(v2.w) + hlo(v3.w);
    a7 += hhi(v0.w) + hhi(v1.w) + hhi(v2.w) + hhi(v3.w);
  }
  for (; j < e; ++j) {
    uint4 v = h4[(size_t)col[j] * 16 + li];
    a0 += hlo(v.x);
    a1 += hhi(v.x);
    a2 += hlo(v.y);
    a3 += hhi(v.y);
    a4 += hlo(v.z);
    a5 += hhi(v.z);
    a6 += hlo(v.w);
    a7 += hhi(v.w);
  }
  float4 b0 = ((const float4*)b)[li * 2];
  float4 b1 = ((const float4*)b)[li * 2 + 1];
  float r0 = dv * a0 + b0.x;
  float r1 = dv * a1 + b0.y;
  float r2 = dv * a2 + b0.z;
  float r3 = dv * a3 + b0.w;
  float r4 = dv * a4 + b1.x;
  float r5 = dv * a5 + b1.y;
  float r6 = dv * a6 + b1.z;
  float r7 = dv * a7 + b1.w;
  float ss = r0 * r0 + r1 * r1 + r2 * r2 + r3 * r3 +
             r4 * r4 + r5 * r5 + r6 * r6 + r7 * r7;
#pragma unroll
  for (int off = 8; off; off >>= 1) ss += __shfl_xor(ss, off);  // 16-lane reduce
  float inv = 1.0f / fmaxf(sqrtf(ss), 1e-8f);
  uint4 o;
  o.x = (unsigned int)f2h(r0 * inv) | ((unsigned int)f2h(r1 * inv) << 16);
  o.y = (unsigned int)f2h(r2 * inv) | ((unsigned int)f2h(r3 * inv) << 16);
  o.z = (unsigned int)f2h(r4 * inv) | ((unsigned int)f2h(r5 * inv) << 16);
  o.w = (unsigned int)f2h(r6 * inv) | ((unsigned int)f2h(r7 * inv) << 16);
  ((uint4*)xn)[(size_t)node * 16 + li] = o;
}

// ---- classifier fp16 MFMA GEMM: out = xn @ clsn^T ----
__global__ __launch_bounds__(256) void k_outg(const unsigned short* __restrict__ xn,
                                              const unsigned short* __restrict__ clsp,
                                              float* __restrict__ out) {
  int tid = threadIdx.x;
  int lane = tid & 63;
  int wid = tid >> 6;
  int l15 = lane & 15, lhi = lane >> 4;
  int bm0 = blockIdx.x * 128 + wid * 32;

  f4v acc[2][4];
#pragma unroll
  for (int m = 0; m < 2; ++m)
#pragma unroll
    for (int nf = 0; nf < 4; ++nf) acc[m][nf] = f4v{0.f, 0.f, 0.f, 0.f};

#pragma unroll
  for (int ks = 0; ks < 4; ++ks) {
    h8v a[2];
#pragma unroll
    for (int m = 0; m < 2; ++m) {
      int row = bm0 + m * 16 + l15;
      a[m] = (row < NN)
                 ? *reinterpret_cast<const h8v*>(&xn[(size_t)row * DD + ks * 32 + lhi * 8])
                 : hzero();
    }
#pragma unroll
    for (int nf = 0; nf < 4; ++nf) {
      int n = nf * 16 + l15;
      h8v b = *reinterpret_cast<const h8v*>(&clsp[(size_t)n * DD + ks * 32 + lhi * 8]);
#pragma unroll
      for (int m = 0; m < 2; ++m)
        acc[m][nf] = __builtin_amdgcn_mfma_f32_16x16x32_f16(a[m], b, acc[m][nf], 0, 0, 0);
    }
  }
#pragma unroll
  for (int m = 0; m < 2; ++m)
#pragma unroll
    for (int nf = 0; nf < 4; ++nf) {
      int colx = nf * 16 + l15;
      int rowb = bm0 + m * 16 + lhi * 4;
#pragma unroll
      for (int j = 0; j < 4; ++j) {
        int row = rowb + j;
        if (row < NN) out[(size_t)row * CC + colx] = acc[m][nf][j];
      }
    }
}

extern "C" void kernel_launch(void* const* d_in, const int* in_sizes, int n_in,
                              void* d_out, int out_size, void* d_ws, size_t ws_size,
                              hipStream_t stream) {
  const float* xE = (const float*)d_in[0];
  const float* xH = (const float*)d_in[1];
  const float* xS = (const float*)d_in[2];
  const int* ei = (const int*)d_in[3];
  const float* W = (const float*)d_in[4];
  const float* b = (const float*)d_in[5];
  const float* cls = (const float*)d_in[6];
  float* out = (float*)d_out;

  char* ws = (char*)d_ws;
  size_t off = 0;
  auto alloc = [&](size_t bytes) {
    void* p = ws + off;
    off = (off + bytes + 255) & ~(size_t)255;
    return p;
  };
  unsigned short* h = (unsigned short*)alloc((size_t)NN * DD * 2);
  unsigned int* xn = (unsigned int*)alloc((size_t)NN * 64 * 4);
  float* dinv = (float*)alloc((size_t)NN * 4);
  float* chv = (float*)alloc((size_t)NN * 4);
  float* csv = (float*)alloc((size_t)NN * 4);
  int* cnt = (int*)alloc((size_t)(NN + 16) * 4);
  int* rowst = (int*)alloc((size_t)(NN + 1) * 4);
  unsigned short* rank = (unsigned short*)alloc((size_t)EE * 2);
  unsigned short* col = (unsigned short*)alloc((size_t)EE * 2);
  unsigned short* Wt = (unsigned short*)alloc((size_t)DD * IND * 2);
  unsigned int* clsp = (unsigned int*)alloc((size_t)CC * 64 * 4);
  int* bsum = (int*)alloc(64 * 4);

  const int* esrc = ei;
  const int* edst = ei + EE;
  const int NB = (NN + 1023) / 1024;   // 49
  const int N4 = (NN + 3) / 4;
  const int ZB = (N4 + 255) / 256;

  k_prep<<<SCAL_B + WT_B + 1 + ZB, 256, 0, stream>>>(W, cls, xH, xS, Wt, clsp,
                                                     chv, csv, (int4*)cnt, N4);
  k_count<<<(EE / 4 + 255) / 256, 256, 0, stream>>>(edst, cnt, rank);
  k_scan1<<<NB, 1024, 0, stream>>>(cnt, rowst, dinv, bsum);
  k_scan3<<<NB, 1024, 0, stream>>>(rowst, bsum, NB, dinv, chv, csv);
  k_place<<<(EE / 4 + 255) / 256, 256, 0, stream>>>(esrc, edst, rank, rowst, col);
  k_gemm<<<(NN + 31) / 32, 256, 0, stream>>>(xE, xH, xS, dinv, chv, csv, Wt, h);
  k_aggn<<<(NN + 15) / 16, 256, 0, stream>>>(h, rowst, col, dinv, b, xn);
  k_outg<<<(NN + 127) / 128, 256, 0, stream>>>((const unsigned short*)xn,
                                               (const unsigned short*)clsp, out);
}